// Round 9
// baseline (439.778 us; speedup 1.0000x reference)
//
#include <hip/hip_runtime.h>
#include <cstdint>
#include <cstddef>

// ---------------- problem constants ----------------
#define TGT   24
#define BS    16
#define SRC   400
#define VOCABN 32000
#define DIM   256
#define NROW  (TGT*BS)   // 384
#define LSTM_NBLK 4

typedef __bf16 bf16_t;
typedef __bf16 v8bf __attribute__((ext_vector_type(8)));
typedef float  v4f  __attribute__((ext_vector_type(4)));
typedef unsigned int u32;
typedef unsigned short u16;

__device__ __forceinline__ float fast_tanh(float x) {
    // monotone, no NaN for large |x|: e->0 => -1, e->inf => +1
    float e = __expf(2.f*x);
    return 1.f - 2.f/(e + 1.f);
}

// ---------------- prep: dtype conversions / transposes / gather ----------------
// Also zeroes the barrier counter + rsum (replaces the old hipMemsetAsync) and
// emits h0 as packed (hi | lo<<16) u32 for the LSTM's coherence-point exchange.
__global__ void k_prep(const float* __restrict__ Whh, const float* __restrict__ Wad,
                       const float* __restrict__ he,  const float* __restrict__ Wemb,
                       const float* __restrict__ Wproj, const float* __restrict__ Wae,
                       const float* __restrict__ Wih, const int* __restrict__ inputs,
                       const float* __restrict__ h0,
                       bf16_t* o_whh, bf16_t* o_wadT, bf16_t* o_he, bf16_t* o_heT,
                       bf16_t* o_wae, bf16_t* o_wih, bf16_t* o_wprojT, bf16_t* o_embA,
                       u32* o_hpk, u32* o_zero)
{
    const long S0=262144, S1=65536, S2=1638400, S3=1638400, S4=65536, S5=262144, S6=196608, S7=98304, S8=4096, S9=768;
    const long total = S0+S1+S2+S3+S4+S5+S6+S7+S8+S9;
    for (long i = (long)blockIdx.x*blockDim.x + threadIdx.x; i < total;
         i += (long)gridDim.x*blockDim.x) {
        long j = i;
        if (j < S0) { o_whh[j] = (bf16_t)Whh[j]; continue; }           j -= S0;
        if (j < S1) { long n = j>>8, k = j&255; o_wadT[j] = (bf16_t)Wad[k*DIM + n]; continue; } j -= S1;
        if (j < S2) { o_he[j] = (bf16_t)he[j]; continue; }             j -= S2;
        if (j < S3) { // heT[b][d][s] = he[(s*BS+b)*DIM+d]
            long b = j / 102400, rem = j % 102400, d = rem / 400, s = rem % 400;
            o_heT[j] = (bf16_t)he[(s*BS + b)*DIM + d]; continue; }     j -= S3;
        if (j < S4) { o_wae[j] = (bf16_t)Wae[j]; continue; }           j -= S4;
        if (j < S5) { o_wih[j] = (bf16_t)Wih[j]; continue; }           j -= S5;
        if (j < S6) { long n = j>>8, k = j&255; o_wprojT[j] = (bf16_t)Wproj[k*768 + n]; continue; } j -= S6;
        if (j < S7) { long r = j>>8, k = j&255; o_embA[j] = (bf16_t)Wemb[(long)inputs[r]*DIM + k]; continue; } j -= S7;
        if (j < S8) { // h0 -> packed (hi | lo<<16), [16][256]
            float v = h0[j];
            bf16_t hi = (bf16_t)v;
            bf16_t lo = (bf16_t)(v - (float)hi);
            o_hpk[j] = (u32)(*(const u16*)&hi) | ((u32)(*(const u16*)&lo) << 16);
            continue; }                                                j -= S8;
        o_zero[j] = 0;   // barrier counter + rsum region (3072 B)
    }
}

// ---------------- generic bf16 MFMA GEMM tile, 128x128, BK=32 (device body) ----
// C[M,N] = A[M,K] @ B[N,K]^T  (row-major, K-contiguous). A32!=null: A read fp32.
// mode 0: fp32 out + bias0 + bias1
// mode 1: bf16 out, tanh
// mode 2: bf16 out
// mode 4: fp32 out + bias0 + bias1, written TRANSPOSED-per-gate for the LSTM:
//         out[row*1024 + (col&255)*4 + (col>>8)]   (N must be 1024)
__device__ __forceinline__ void gemm_tile(
    const int tid, bf16_t* As, bf16_t* Bs,
    const bf16_t* __restrict__ A, const float* __restrict__ A32,
    const bf16_t* __restrict__ B,
    const int tileIdx, const int N, const int K, const int Ntiles, const int mode,
    float* __restrict__ outF, bf16_t* __restrict__ outB,
    const float* __restrict__ bias0, const float* __restrict__ bias1)
{
    const int mt   = tileIdx / Ntiles, nt = tileIdx % Ntiles;
    const int m0   = mt*128, n0 = nt*128;
    const int lane = tid & 63, wave = tid >> 6;
    const int wm   = wave >> 1, wn = wave & 1;
    const int quad = lane >> 4, l16 = lane & 15;

    v4f acc[4][4];
#pragma unroll
    for (int i=0;i<4;i++)
#pragma unroll
        for (int j=0;j<4;j++) acc[i][j] = (v4f){0.f,0.f,0.f,0.f};

    const int srow = tid >> 1, shalf = tid & 1;       // staging: 2 threads/row
    const bf16_t* Ag   = A   ? A   + (size_t)(m0+srow)*K + shalf*16 : nullptr;
    const float*  Ag32 = A32 ? A32 + (size_t)(m0+srow)*K + shalf*16 : nullptr;
    const bf16_t* Bg = B + (size_t)(n0+srow)*K + shalf*16;
    bf16_t* AsW = &As[srow*40 + shalf*16];
    bf16_t* BsW = &Bs[srow*40 + shalf*16];

    for (int kc = 0; kc < K; kc += 32) {
        __syncthreads();
        uint4 b0 = *(const uint4*)(Bg + kc);
        uint4 b1 = *(const uint4*)(Bg + kc + 8);
        if (A32) {
            float4 f0 = *(const float4*)(Ag32 + kc);
            float4 f1 = *(const float4*)(Ag32 + kc + 4);
            float4 f2 = *(const float4*)(Ag32 + kc + 8);
            float4 f3 = *(const float4*)(Ag32 + kc + 12);
            v8bf u0, u1;
            u0[0]=(bf16_t)f0.x; u0[1]=(bf16_t)f0.y; u0[2]=(bf16_t)f0.z; u0[3]=(bf16_t)f0.w;
            u0[4]=(bf16_t)f1.x; u0[5]=(bf16_t)f1.y; u0[6]=(bf16_t)f1.z; u0[7]=(bf16_t)f1.w;
            u1[0]=(bf16_t)f2.x; u1[1]=(bf16_t)f2.y; u1[2]=(bf16_t)f2.z; u1[3]=(bf16_t)f2.w;
            u1[4]=(bf16_t)f3.x; u1[5]=(bf16_t)f3.y; u1[6]=(bf16_t)f3.z; u1[7]=(bf16_t)f3.w;
            *(v8bf*)AsW = u0; *(v8bf*)(AsW+8) = u1;
        } else {
            uint4 a0 = *(const uint4*)(Ag + kc);
            uint4 a1 = *(const uint4*)(Ag + kc + 8);
            *(uint4*)AsW = a0; *(uint4*)(AsW+8) = a1;
        }
        *(uint4*)BsW = b0; *(uint4*)(BsW+8) = b1;
        __syncthreads();
        v8bf af[4], bb[4];
#pragma unroll
        for (int i=0;i<4;i++) {
            af[i] = *(const v8bf*)&As[(wm*64 + i*16 + l16)*40 + quad*8];
            bb[i] = *(const v8bf*)&Bs[(wn*64 + i*16 + l16)*40 + quad*8];
        }
#pragma unroll
        for (int i=0;i<4;i++)
#pragma unroll
            for (int j=0;j<4;j++)
                acc[i][j] = __builtin_amdgcn_mfma_f32_16x16x32_bf16(af[i], bb[j], acc[i][j], 0,0,0);
    }

#pragma unroll
    for (int i=0;i<4;i++) {
#pragma unroll
        for (int j=0;j<4;j++) {
#pragma unroll
            for (int r=0;r<4;r++) {
                const int gr = m0 + wm*64 + i*16 + quad*4 + r;   // C/D row = quad*4+reg
                const int gc = n0 + wn*64 + j*16 + l16;          // C/D col = lane&15
                const float v = acc[i][j][r];
                if (mode == 0)      outF[(size_t)gr*N + gc] = v + bias0[gc] + bias1[gc];
                else if (mode == 1) outB[(size_t)gr*N + gc] = (bf16_t)fast_tanh(v);
                else if (mode == 2) outB[(size_t)gr*N + gc] = (bf16_t)v;
                else if (mode == 4) outF[(size_t)gr*N + (gc & 255)*4 + (gc >> 8)] = v + bias0[gc] + bias1[gc];
            }
        }
    }
}

// combined xg (mode 4, 24 tiles) + ke (mode 2, 100 tiles) — both depend only
// on k_prep, so they share one launch.
__global__ __launch_bounds__(256) void k_gemm2(
    const bf16_t* __restrict__ embA, const bf16_t* __restrict__ wih,
    float* __restrict__ xg, const float* __restrict__ b_ih, const float* __restrict__ b_hh,
    const bf16_t* __restrict__ heA, const bf16_t* __restrict__ waeB, bf16_t* __restrict__ keB)
{
    __shared__ bf16_t As[128*40];
    __shared__ bf16_t Bs[128*40];
    if (blockIdx.x < 24)
        gemm_tile(threadIdx.x, As, Bs, embA, nullptr, wih, blockIdx.x, 1024, 256, 8, 4,
                  xg, nullptr, b_ih, b_hh);
    else
        gemm_tile(threadIdx.x, As, Bs, heA, nullptr, waeB, blockIdx.x - 24, 256, 256, 2, 2,
                  nullptr, keB, nullptr, nullptr);
}

// ---------------- dedicated logits GEMM: exp(feat@wout^T + b_out), rsum -------
// M=384, N=32000, K=768. BK=64, pitch-72 LDS. mode-3 epilogue.
__global__ __launch_bounds__(256) void k_gemm3(
    const bf16_t* __restrict__ A, const bf16_t* __restrict__ B,
    float* __restrict__ outF, const float* __restrict__ bias0,
    const int* __restrict__ padp, float* __restrict__ rsum)
{
    __shared__ bf16_t As[128*72];
    __shared__ bf16_t Bs[128*72];
    const int tid = threadIdx.x;
    const int mt = blockIdx.x / 250, nt = blockIdx.x % 250;
    const int m0 = mt*128, n0 = nt*128;
    const int lane = tid & 63, wave = tid >> 6;
    const int wm = wave >> 1, wn = wave & 1;
    const int quad = lane >> 4, l16 = lane & 15;

    v4f acc[4][4];
#pragma unroll
    for (int i=0;i<4;i++)
#pragma unroll
        for (int j=0;j<4;j++) acc[i][j] = (v4f){0.f,0.f,0.f,0.f};

    const int srow = tid >> 1, shalf = tid & 1;       // 2 threads/row, 64B each
    const bf16_t* Ag = A + (size_t)(m0+srow)*768 + shalf*32;
    const bf16_t* Bg = B + (size_t)(n0+srow)*768 + shalf*32;
    bf16_t* AsW = &As[srow*72 + shalf*32];
    bf16_t* BsW = &Bs[srow*72 + shalf*32];

    for (int kc = 0; kc < 768; kc += 64) {
        __syncthreads();
        uint4 a0 = *(const uint4*)(Ag + kc);
        uint4 a1 = *(const uint4*)(Ag + kc + 8);
        uint4 a2 = *(const uint4*)(Ag + kc + 16);
        uint4 a3 = *(const uint4*)(Ag + kc + 24);
        uint4 b0 = *(const uint4*)(Bg + kc);
        uint4 b1 = *(const uint4*)(Bg + kc + 8);
        uint4 b2 = *(const uint4*)(Bg + kc + 16);
        uint4 b3 = *(const uint4*)(Bg + kc + 24);
        *(uint4*)(AsW)    = a0; *(uint4*)(AsW+8)  = a1;
        *(uint4*)(AsW+16) = a2; *(uint4*)(AsW+24) = a3;
        *(uint4*)(BsW)    = b0; *(uint4*)(BsW+8)  = b1;
        *(uint4*)(BsW+16) = b2; *(uint4*)(BsW+24) = b3;
        __syncthreads();
#pragma unroll
        for (int kk = 0; kk < 2; ++kk) {
            v8bf af[4], bb[4];
#pragma unroll
            for (int i=0;i<4;i++) {
                af[i] = *(const v8bf*)&As[(wm*64 + i*16 + l16)*72 + kk*32 + quad*8];
                bb[i] = *(const v8bf*)&Bs[(wn*64 + i*16 + l16)*72 + kk*32 + quad*8];
            }
#pragma unroll
            for (int i=0;i<4;i++)
#pragma unroll
                for (int j=0;j<4;j++)
                    acc[i][j] = __builtin_amdgcn_mfma_f32_16x16x32_bf16(af[i], bb[j], acc[i][j], 0,0,0);
        }
    }

    const int pad = *padp;
    float* rs = (float*)As;          // LDS reuse for row partial sums
    __syncthreads();
    if (tid < 128) rs[tid] = 0.f;
    __syncthreads();
#pragma unroll
    for (int i=0;i<4;i++) {
        float rloc[4] = {0.f,0.f,0.f,0.f};
#pragma unroll
        for (int j=0;j<4;j++) {
#pragma unroll
            for (int r=0;r<4;r++) {
                const int gr = m0 + wm*64 + i*16 + quad*4 + r;
                const int gc = n0 + wn*64 + j*16 + l16;
                const float ex = (gc == pad) ? 0.f : __expf(acc[i][j][r] + bias0[gc]);
                outF[(size_t)gr*VOCABN + gc] = ex;
                rloc[r] += ex;
            }
        }
#pragma unroll
        for (int r=0;r<4;r++)
            atomicAdd(&rs[wm*64 + i*16 + quad*4 + r], rloc[r]);
    }
    __syncthreads();
    if (tid < 128) atomicAdd(&rsum[m0 + tid], rs[tid]);
}

// ---------------- device-scope grid barrier (monotonic counter) ----------------
__device__ __forceinline__ void gridbar(int* bar, int target) {
    __syncthreads();
    if (threadIdx.x == 0) {
        __threadfence();   // release: publish this block's h stores device-wide
        __hip_atomic_fetch_add(bar, 1, __ATOMIC_ACQ_REL, __HIP_MEMORY_SCOPE_AGENT);
        while (__hip_atomic_load(bar, __ATOMIC_ACQUIRE, __HIP_MEMORY_SCOPE_AGENT) < target) { }
        __threadfence();   // acquire: invalidate stale L1/L2 before h reads
    }
    __syncthreads();
}

// ---------------- sequential LSTM chain: 4 cooperating CUs, reg-resident W_hh --
// R5 structure (150us) with the write side moved OFF the L2: the release fence
// lowers to buffer_wbl2 (write back all dirty L2) and its cost scales with
// dirty volume. All loop stores now bypass L2 to the coherence point:
//   - h exchange: packed (hi|lo<<16) u32, ONE relaxed agent-scope atomic store
//     (R7 showed uncached LOADS are the poison, not stores — h reads stay
//     plain cached loads; the gridbar's buffer_inv guarantees freshness).
//   - hallF: deferred past the barrier, relaxed atomic u32 stores.
//   - hallB: ELIMINATED (qd GEMM uses gemm_tile's A32 path on hallF).
// Per-step dirty L2 ~0 -> wbl2 cheap. Fences unchanged (correctness identical,
// placement-independent).
__global__ __launch_bounds__(512, 2) void k_lstm(
    const bf16_t* __restrict__ Whh, const float* __restrict__ xgT,
    const float* __restrict__ c0,
    u32* __restrict__ hpk,           // [16][256] packed (hi | lo<<16)
    float* __restrict__ hallF,
    int* __restrict__ bar)
{
    __shared__ float gl[16][260];   // pre-activation exchange, padded

    const int tid = threadIdx.x;
    const int k = blockIdx.x;            // d-slice owner
    const int w = tid >> 6, lane = tid & 63;
    const int l16 = lane & 15, quad = lane >> 4;

    // B-fragments: wave w owns CU-local cols c in [w*32, w*32+32), ct in {0,1}
    v8bf wb[2][8];
#pragma unroll
    for (int ct = 0; ct < 2; ++ct) {
        const int c = w*32 + ct*16 + l16;
        const int row = (c >> 6)*256 + k*64 + (c & 63);
#pragma unroll
        for (int kc = 0; kc < 8; ++kc)
            wb[ct][kc] = *(const v8bf*)&Whh[(size_t)row*DIM + kc*32 + quad*8];
    }

    float cst[2];
#pragma unroll
    for (int e = 0; e < 2; ++e) {
        const int li = tid + e*512;
        cst[e] = c0[(li >> 6)*DIM + k*64 + (li & 63)];
    }

    for (int step = 0; step < TGT; ++step) {
        // packed h loads (plain cached; gridbar's inv guarantees freshness)
        uint4 pq[8][2];
#pragma unroll
        for (int kc = 0; kc < 8; ++kc) {
            const uint4* pp = (const uint4*)&hpk[l16*DIM + kc*32 + quad*8];
            pq[kc][0] = pp[0]; pq[kc][1] = pp[1];
        }
        // xv: 4 gates of xg for the two owned elements (float4, coalesced)
        float4 xv[2];
#pragma unroll
        for (int e = 0; e < 2; ++e) {
            const int li = tid + e*512;
            const int b = li >> 6, dd = li & 63;
            xv[e] = *(const float4*)&xgT[((size_t)(step*BS + b)*DIM + k*64 + dd)*4];
        }
        // unpack hi/lo
        v8bf ahi[8], alo[8];
#pragma unroll
        for (int kc = 0; kc < 8; ++kc) {
            const u32 uu[8] = {pq[kc][0].x, pq[kc][0].y, pq[kc][0].z, pq[kc][0].w,
                               pq[kc][1].x, pq[kc][1].y, pq[kc][1].z, pq[kc][1].w};
#pragma unroll
            for (int j = 0; j < 8; ++j) {
                union { u32 u; u16 s[2]; } x; x.u = uu[j];
                ahi[kc][j] = *(const bf16_t*)&x.s[0];
                alo[kc][j] = *(const bf16_t*)&x.s[1];
            }
        }

        v4f acc[2] = {(v4f){0.f,0.f,0.f,0.f}, (v4f){0.f,0.f,0.f,0.f}};
#pragma unroll
        for (int kc = 0; kc < 8; ++kc)
#pragma unroll
            for (int ct = 0; ct < 2; ++ct) {
                acc[ct] = __builtin_amdgcn_mfma_f32_16x16x32_bf16(ahi[kc], wb[ct][kc], acc[ct], 0,0,0);
                acc[ct] = __builtin_amdgcn_mfma_f32_16x16x32_bf16(alo[kc], wb[ct][kc], acc[ct], 0,0,0);
            }
        // exchange pre-activations: C row = quad*4+r (b), col = l16 (c-in-tile)
#pragma unroll
        for (int ct = 0; ct < 2; ++ct) {
            const int c = w*32 + ct*16 + l16;
#pragma unroll
            for (int r = 0; r < 4; ++r)
                gl[quad*4 + r][c] = acc[ct][r];
        }
        __syncthreads();
        // elementwise: thread owns (b, dd) and (b+8, dd)
        float hnv[2];
#pragma unroll
        for (int e = 0; e < 2; ++e) {
            const int li = tid + e*512;
            const int b = li >> 6, dd = li & 63;
            const int d = k*64 + dd;
            const float gi = gl[b][dd]        + xv[e].x;
            const float gf = gl[b][64 + dd]   + xv[e].y;
            const float gg = gl[b][128 + dd]  + xv[e].z;
            const float go = gl[b][192 + dd]  + xv[e].w;
            const float si = 1.f/(1.f+__expf(-gi));
            const float sf = 1.f/(1.f+__expf(-gf));
            const float so = 1.f/(1.f+__expf(-go));
            const float cn = sf*cst[e] + si*fast_tanh(gg);
            const float hn = so*fast_tanh(cn);
            cst[e] = cn;
            hnv[e] = hn;
            const bf16_t hi = (bf16_t)hn;
            const bf16_t lo = (bf16_t)(hn - (float)hi);
            const u32 pk = (u32)(*(const u16*)&hi) | ((u32)(*(const u16*)&lo) << 16);
            __hip_atomic_store(&hpk[b*DIM + d], pk, __ATOMIC_RELAXED, __HIP_MEMORY_SCOPE_AGENT);
        }
        if (step < TGT-1) gridbar(bar, (step+1)*LSTM_NBLK);
        // deferred hallF stores: coherence-point writes (no L2 dirt), off the
        // pre-arrival drain path; final step covered by end-of-kernel release
#pragma unroll
        for (int e = 0; e < 2; ++e) {
            const int li = tid + e*512;
            const int b = li >> 6, dd = li & 63;
            const int d = k*64 + dd;
            union { float f; u32 u; } cv; cv.f = hnv[e];
            __hip_atomic_store((u32*)&hallF[(size_t)(step*BS + b)*DIM + d], cv.u,
                               __ATOMIC_RELAXED, __HIP_MEMORY_SCOPE_AGENT);
        }
    }
}

// ---------------- expE[t,b,s] = exp(ke[s,b,:] . h[t,b,:]) (device body) --------
__device__ __forceinline__ void escore_body(const int blk, const int tid, float* hS,
    const bf16_t* __restrict__ ke, const float* __restrict__ hallF, float* __restrict__ expE)
{
    const int t = blk >> 4, b = blk & 15;
    hS[tid] = hallF[(size_t)(t*BS + b)*DIM + tid];
    __syncthreads();
    for (int s = tid; s < SRC; s += 256) {
        const v8bf* kp = (const v8bf*)(ke + ((size_t)s*BS + b)*DIM);
        float e = 0.f;
#pragma unroll 8
        for (int m=0;m<32;m++) {
            v8bf kv = kp[m];
#pragma unroll
            for (int i=0;i<8;i++) e += (float)kv[i]*hS[m*8+i];
        }
        expE[((size_t)t*BS + b)*SRC + s] = __expf(e);
    }
}

// fused escore + qd GEMM (qd = h_all @ W_attn_dec, 6 tiles, A32 from hallF)
__global__ __launch_bounds__(256) void k_esq(
    const bf16_t* __restrict__ ke, const float* __restrict__ hallF, float* __restrict__ expE,
    const bf16_t* __restrict__ wadT, bf16_t* __restrict__ qdG)
{
    __shared__ __align__(16) char shb[20480];
    if (blockIdx.x < NROW) {
        escore_body(blockIdx.x, threadIdx.x, (float*)shb, ke, hallF, expE);
        return;
    }
    gemm_tile(threadIdx.x, (bf16_t*)shb, (bf16_t*)(shb + 10240), nullptr, hallF, wadT,
              blockIdx.x - NROW, 256, 256, 2, 2, nullptr, qdG, nullptr, nullptr);
}

// ---------------- in-place inclusive cumulative sum of expE over t ------------
__global__ __launch_bounds__(256) void k_prefix(float* __restrict__ expE)
{
    const int i = blockIdx.x*256 + threadIdx.x;   // flat (b,s)
    if (i >= BS*SRC) return;
    const int b = i / SRC, s = i % SRC;
    float c = 0.f;
    for (int t = 0; t < TGT; ++t) {
        const size_t idx = ((size_t)t*BS + b)*SRC + s;
        c += expE[idx];
        expE[idx] = c;
    }
}

// ---------------- per-(t,b) attention tail (device body) ----------------
// cumE is the CUMULATIVE expE: my = cum[t]-cum[t-1], prev-sum = cum[t-1].
__device__ void attn_body(char* sh, const int blk, const int tid,
    const float* __restrict__ cumE, const bf16_t* __restrict__ heT,
    const float* __restrict__ hallF, const bf16_t* __restrict__ qdG,
    const float* __restrict__ wu, const float* __restrict__ bu,
    bf16_t* __restrict__ feat, float* __restrict__ Ae, float* __restrict__ ps)
{
    float* hS   = (float*)sh;        // 256
    float* qdS  = hS + 256;          // 256
    float* eeS  = qdS + 256;         // 400
    float* adS  = eeS + 400;         // 24
    float* red  = adS + 24;          // 4
    float* misc = red + 4;           // 2
    const int t = blk >> 4, b = blk & 15;

    hS[tid]  = hallF[(size_t)(t*BS + b)*DIM + tid];
    qdS[tid] = (float)qdG[(size_t)(t*BS + b)*DIM + tid];
    __syncthreads();

    for (int s = tid; s < SRC; s += 256) {
        if (t == 0) {
            eeS[s] = cumE[(size_t)b*SRC + s];               // cum[0] == raw expE
        } else {
            const float prev = cumE[((size_t)(t-1)*BS + b)*SRC + s];
            const float cur  = cumE[((size_t)t*BS + b)*SRC + s];
            eeS[s] = (cur - prev) / prev;
        }
    }
    __syncthreads();
    {   // esum
        float pa = 0.f;
        for (int s = tid; s < SRC; s += 256) pa += eeS[s];
#pragma unroll
        for (int o=32;o>0;o>>=1) pa += __shfl_down(pa, o);
        if ((tid & 63) == 0) red[tid>>6] = pa;
        __syncthreads();
        if (tid == 0) misc[0] = 1.f/(red[0]+red[1]+red[2]+red[3]);
        __syncthreads();
    }
    const float inv_es = misc[0];
    for (int s = tid; s < SRC; s += 256)
        Ae[((size_t)t*BS + b)*SRC + s] = eeS[s] * inv_es;

    float ce;
    {
        const v8bf* hp = (const v8bf*)(heT + ((size_t)b*DIM + tid)*SRC);
        float acc = 0.f;
#pragma unroll 10
        for (int m=0;m<50;m++) {
            v8bf hv = hp[m];
#pragma unroll
            for (int i=0;i<8;i++) acc += (float)hv[i]*eeS[m*8+i];
        }
        ce = acc * inv_es;
    }

    {
        const int wv = tid >> 6, ln = tid & 63;
        for (int tau = wv; tau <= t; tau += 4) {
            float4 a = *(const float4*)(hallF + ((size_t)(tau*BS + b))*DIM + ln*4);
            float e = a.x*qdS[ln*4] + a.y*qdS[ln*4+1] + a.z*qdS[ln*4+2] + a.w*qdS[ln*4+3];
#pragma unroll
            for (int o=32;o>0;o>>=1) e += __shfl_down(e, o);
            if (ln == 0) adS[tau] = __expf(e);
        }
    }
    __syncthreads();
    if (tid < 64) {
        float v = (tid <= t) ? adS[tid] : 0.f;
#pragma unroll
        for (int o=32;o>0;o>>=1) v += __shfl_down(v, o);
        if (tid == 0) misc[1] = 1.f/v;
    }
    __syncthreads();
    float cd = 0.f;
    for (int tau = 0; tau <= t; ++tau)
        cd += adS[tau] * hallF[((size_t)(tau*BS + b))*DIM + tid];
    cd *= misc[1];
    if (t == 0) cd = 0.f;

    const float hd = hS[tid];
    const size_t fr = ((size_t)t*BS + b)*768;
    feat[fr + tid]       = (bf16_t)hd;
    feat[fr + 256 + tid] = (bf16_t)ce;
    feat[fr + 512 + tid] = (bf16_t)cd;
    float pw = hd*wu[tid] + ce*wu[256 + tid] + cd*wu[512 + tid];
#pragma unroll
    for (int o=32;o>0;o>>=1) pw += __shfl_down(pw, o);
    if ((tid & 63) == 0) red[tid>>6] = pw;
    __syncthreads();
    if (tid == 0) {
        float s = red[0]+red[1]+red[2]+red[3];
        ps[t*BS + b] = 1.f/(1.f+__expf(-(s + bu[0])));
    }
}

// ---------------- fused: attention tail (blocks 0-383) + W_out tiles (384-1883) -
__global__ __launch_bounds__(256) void k_attnw(
    const float* __restrict__ cumE, const bf16_t* __restrict__ heT,
    const float* __restrict__ hallF, const bf16_t* __restrict__ qdG,
    const float* __restrict__ wu, const float* __restrict__ bu,
    bf16_t* __restrict__ feat, float* __restrict__ Ae, float* __restrict__ ps,
    const float* __restrict__ Wemb, const bf16_t* __restrict__ wprojT,
    bf16_t* __restrict__ woutB)
{
    __shared__ __align__(16) char shb[20480];
    if (blockIdx.x < NROW) {
        attn_body(shb, blockIdx.x, threadIdx.x, cumE, heT, hallF, qdG, wu, bu, feat, Ae, ps);
        return;
    }
    gemm_tile(threadIdx.x, (bf16_t*)shb, (bf16_t*)(shb + 10240), nullptr, Wemb, wprojT,
              blockIdx.x - NROW, 768, 256, 6, 1,
              nullptr, woutB, nullptr, nullptr);
}

// ---------------- final: scale row by ps[r]/rsum[r], then copy-scatter ---------
__global__ __launch_bounds__(256) void k_final(
    float* __restrict__ out, const float* __restrict__ rsum,
    const float* __restrict__ ps, const int* __restrict__ src,
    const float* __restrict__ Ae)
{
    const int r = blockIdx.x;        // r = t*BS + b
    const int b = r & (BS-1);
    const float p  = ps[r];
    const float sc = p / rsum[r];
    float4* o4 = (float4*)(out + (size_t)r*VOCABN);
    for (int i = threadIdx.x; i < VOCABN/4; i += 256) {
        float4 v = o4[i];
        v.x*=sc; v.y*=sc; v.z*=sc; v.w*=sc;
        o4[i] = v;
    }
    __syncthreads();   // row fully scaled before scatter into it
    for (int s = threadIdx.x; s < SRC; s += 256) {
        const int v = src[s*BS + b];
        atomicAdd(&out[(size_t)r*VOCABN + v], Ae[(size_t)r*SRC + s] * p);
    }
}

// ---------------- workspace layout (bytes, 16B-aligned) ----------------
#define O_WHH    0u
#define O_WADT   524288u
#define O_HEBF   655360u
#define O_HET    3932160u
#define O_KE     7208960u
#define O_WAE    10485760u
#define O_WPROJT 10616832u
#define O_WIH    11010048u
#define O_EMBA   11534336u
#define O_WOUT   11730944u
#define O_XG     60882944u
#define O_HALLF  62455808u
#define O_QD     63045632u
#define O_EXPE   63242240u   // first 16 KB double as hpk (packed h) during k_lstm
#define O_FEAT   63856640u
#define O_AE     64446464u
#define O_PS     65060864u
#define O_BAR    65062400u   // barrier counter + rsum, zeroed by k_prep each call
#define O_RSUM   65063936u

extern "C" void kernel_launch(void* const* d_in, const int* in_sizes, int n_in,
                              void* d_out, int out_size, void* d_ws, size_t ws_size,
                              hipStream_t stream)
{
    const int*   inputs = (const int*)  d_in[0];
    const int*   src    = (const int*)  d_in[1];
    const float* h_e    = (const float*)d_in[2];
    const float* h0     = (const float*)d_in[3];
    const float* c0     = (const float*)d_in[4];
    const float* W_emb  = (const float*)d_in[5];
    const float* W_ih   = (const float*)d_in[6];
    const float* b_ih   = (const float*)d_in[7];
    const float* W_hh   = (const float*)d_in[8];
    const float* b_hh   = (const float*)d_in[9];
    const float* W_ae   = (const float*)d_in[10];
    const float* W_ad   = (const float*)d_in[11];
    const float* W_proj = (const float*)d_in[12];
    const float* W_u    = (const float*)d_in[13];
    const float* b_u    = (const float*)d_in[14];
    const float* b_out  = (const float*)d_in[15];
    const int*   pad_id = (const int*)  d_in[16];

    char* w = (char*)d_ws;
    bf16_t* whh_bf  = (bf16_t*)(w + O_WHH);
    bf16_t* wadT_bf = (bf16_t*)(w + O_WADT);
    bf16_t* he_bf   = (bf16_t*)(w + O_HEBF);
    bf16_t* heT_bf  = (bf16_t*)(w + O_HET);
    bf16_t* ke_bf   = (bf16_t*)(w + O_KE);
    bf16_t* wae_bf  = (bf16_t*)(w + O_WAE);
    bf16_t* wprojT  = (bf16_t*)(w + O_WPROJT);
    bf16_t* wih_bf  = (bf16_t*)(w + O_WIH);
    bf16_t* embA_bf = (bf16_t*)(w + O_EMBA);
    bf16_t* wout_bf = (bf16_t*)(w + O_WOUT);
    float*  xg      = (float*) (w + O_XG);      // holds xgT: [row][d][gate]
    float*  hallF   = (float*) (w + O_HALLF);
    bf16_t* qdG     = (bf16_t*)(w + O_QD);
    float*  expE    = (float*) (w + O_EXPE);
    u32*    hpk     = (u32*)   (w + O_EXPE);          // 16 KB, dead until k_esq
    bf16_t* feat_bf = (bf16_t*)(w + O_FEAT);
    float*  Ae      = (float*) (w + O_AE);
    float*  ps      = (float*) (w + O_PS);
    int*    bar     = (int*)   (w + O_BAR);
    u32*    zeroreg = (u32*)   (w + O_BAR);           // bar + rsum, 3072 B
    float*  rsum    = (float*) (w + O_RSUM);
    float*  out     = (float*)d_out;

    // prep (+ zeroes bar/rsum, packs h0)
    k_prep<<<1024, 256, 0, stream>>>(W_hh, W_ad, h_e, W_emb, W_proj, W_ae, W_ih, inputs, h0,
                                     whh_bf, wadT_bf, he_bf, heT_bf,
                                     wae_bf, wih_bf, wprojT, embA_bf, hpk, zeroreg);
    // xgT (mode 4, 24 tiles) + ke (mode 2, 100 tiles) in one launch
    k_gemm2<<<124, 256, 0, stream>>>(embA_bf, wih_bf, xg, b_ih, b_hh,
                                     he_bf, wae_bf, ke_bf);
    // cooperative 4-CU LSTM chain, register-resident W_hh, L2-clean writes
    k_lstm<<<LSTM_NBLK, 512, 0, stream>>>(whh_bf, xg, c0, hpk, hallF, bar);
    // fused escore (blocks 0-383) + qd GEMM (blocks 384-389, A32 from hallF)
    k_esq<<<NROW + 6, 256, 0, stream>>>(ke_bf, hallF, expE, wadT_bf, qdG);
    // in-place cumulative sum of expE over t (25 blocks)
    k_prefix<<<25, 256, 0, stream>>>(expE);
    // fused attention tail (0-383) + W_out GEMM (384-1883)
    k_attnw<<<NROW + 1500, 256, 0, stream>>>(expE, heT_bf, hallF, qdG, W_u, b_u,
                                             feat_bf, Ae, ps,
                                             W_emb, wprojT, wout_bf);
    // exp(logits + b_out), pad -> 0, + fused row sums  (M=384, N=32000, K=768)
    k_gemm3<<<750, 256, 0, stream>>>(feat_bf, wout_bf, out, b_out, pad_id, rsum);
    // scale + copy-scatter, one block per row
    k_final<<<NROW, 256, 0, stream>>>(out, rsum, ps, src, Ae);
}

// Round 10
// 414.265 us; speedup vs baseline: 1.0616x; 1.0616x over previous
//
#include <hip/hip_runtime.h>
#include <cstdint>
#include <cstddef>

// ---------------- problem constants ----------------
#define TGT   24
#define BS    16
#define SRC   400
#define VOCABN 32000
#define DIM   256
#define NROW  (TGT*BS)   // 384
#define LSTM_NBLK 4

typedef __bf16 bf16_t;
typedef __bf16 v8bf __attribute__((ext_vector_type(8)));
typedef float  v4f  __attribute__((ext_vector_type(4)));
typedef unsigned int u32;
typedef unsigned short u16;

__device__ __forceinline__ float fast_tanh(float x) {
    // monotone, no NaN for large |x|: e->0 => -1, e->inf => +1
    float e = __expf(2.f*x);
    return 1.f - 2.f/(e + 1.f);
}

// ---------------- prep: dtype conversions / gather (coalesced only) -----------
// Scattered transposes (heT/wprojT/wadT) moved out: heT is ELIMINATED (attn
// reads he_bf directly, coalesced), wprojT/wadT are LDS-tiled transposes in
// k_gemm2. Also zeroes bar+rsum and packs h0.
__global__ void k_prep(const float* __restrict__ Whh, const float* __restrict__ he,
                       const float* __restrict__ Wemb, const float* __restrict__ Wae,
                       const float* __restrict__ Wih, const int* __restrict__ inputs,
                       const float* __restrict__ h0,
                       bf16_t* o_whh, bf16_t* o_he, bf16_t* o_wae, bf16_t* o_wih,
                       bf16_t* o_embA, u32* o_hpk, u32* o_zero)
{
    const long S0=262144, S1=1638400, S2=65536, S3=262144, S4=98304, S5=4096, S6=768;
    const long total = S0+S1+S2+S3+S4+S5+S6;
    for (long i = (long)blockIdx.x*blockDim.x + threadIdx.x; i < total;
         i += (long)gridDim.x*blockDim.x) {
        long j = i;
        if (j < S0) { o_whh[j] = (bf16_t)Whh[j]; continue; }           j -= S0;
        if (j < S1) { o_he[j] = (bf16_t)he[j]; continue; }             j -= S1;
        if (j < S2) { o_wae[j] = (bf16_t)Wae[j]; continue; }           j -= S2;
        if (j < S3) { o_wih[j] = (bf16_t)Wih[j]; continue; }           j -= S3;
        if (j < S4) { long r = j>>8, k = j&255; o_embA[j] = (bf16_t)Wemb[(long)inputs[r]*DIM + k]; continue; } j -= S4;
        if (j < S5) { // h0 -> packed (hi | lo<<16), [16][256]
            float v = h0[j];
            bf16_t hi = (bf16_t)v;
            bf16_t lo = (bf16_t)(v - (float)hi);
            o_hpk[j] = (u32)(*(const u16*)&hi) | ((u32)(*(const u16*)&lo) << 16);
            continue; }                                                j -= S5;
        o_zero[j] = 0;   // barrier counter + rsum region (3072 B)
    }
}

// ---------------- LDS-tiled fp32 -> bf16 transpose (64x64 tiles) --------------
// out[c][r] = (bf16)in[r][c]. Coalesced loads (float4 rows), 64x65 LDS tile
// (2-way-max bank aliasing = free), coalesced 32B bf16 stores.
__device__ void transpose_tile(const int tid, float* lds /* 64*65 floats */,
                               const float* __restrict__ in, bf16_t* __restrict__ out,
                               const int R, const int C, const int tileIdx)
{
    const int tilesC = C >> 6;
    const int tr = (tileIdx / tilesC) << 6;
    const int tc = (tileIdx % tilesC) << 6;
    const int r0 = tid >> 4;            // 0..15
    const int c0 = (tid & 15) * 4;      // 4 floats/thread
#pragma unroll
    for (int p = 0; p < 4; ++p) {
        const int r = p*16 + r0;
        float4 v = *(const float4*)&in[(size_t)(tr + r)*C + tc + c0];
        lds[r*65 + c0+0] = v.x; lds[r*65 + c0+1] = v.y;
        lds[r*65 + c0+2] = v.z; lds[r*65 + c0+3] = v.w;
    }
    __syncthreads();
    const int oc  = tid >> 2;           // 0..63: output row (col of in)
    const int orr = (tid & 3) * 16;     // 16 elems along r
    bf16_t tmp[16];
#pragma unroll
    for (int k = 0; k < 16; ++k)
        tmp[k] = (bf16_t)lds[(orr + k)*65 + oc];
    bf16_t* op = &out[(size_t)(tc + oc)*R + tr + orr];
    *(uint4*)op       = ((uint4*)tmp)[0];
    *(uint4*)(op + 8) = ((uint4*)tmp)[1];
}

// ---------------- generic bf16 MFMA GEMM tile, 128x128, BK=32 (device body) ----
// C[M,N] = A[M,K] @ B[N,K]^T  (row-major, K-contiguous). A32!=null: A read fp32.
// mode 0: fp32 out + bias0 + bias1
// mode 1: bf16 out, tanh
// mode 2: bf16 out
// mode 4: fp32 out + bias0 + bias1, written TRANSPOSED-per-gate for the LSTM:
//         out[row*1024 + (col&255)*4 + (col>>8)]   (N must be 1024)
__device__ __forceinline__ void gemm_tile(
    const int tid, bf16_t* As, bf16_t* Bs,
    const bf16_t* __restrict__ A, const float* __restrict__ A32,
    const bf16_t* __restrict__ B,
    const int tileIdx, const int N, const int K, const int Ntiles, const int mode,
    float* __restrict__ outF, bf16_t* __restrict__ outB,
    const float* __restrict__ bias0, const float* __restrict__ bias1)
{
    const int mt   = tileIdx / Ntiles, nt = tileIdx % Ntiles;
    const int m0   = mt*128, n0 = nt*128;
    const int lane = tid & 63, wave = tid >> 6;
    const int wm   = wave >> 1, wn = wave & 1;
    const int quad = lane >> 4, l16 = lane & 15;

    v4f acc[4][4];
#pragma unroll
    for (int i=0;i<4;i++)
#pragma unroll
        for (int j=0;j<4;j++) acc[i][j] = (v4f){0.f,0.f,0.f,0.f};

    const int srow = tid >> 1, shalf = tid & 1;       // staging: 2 threads/row
    const bf16_t* Ag   = A   ? A   + (size_t)(m0+srow)*K + shalf*16 : nullptr;
    const float*  Ag32 = A32 ? A32 + (size_t)(m0+srow)*K + shalf*16 : nullptr;
    const bf16_t* Bg = B + (size_t)(n0+srow)*K + shalf*16;
    bf16_t* AsW = &As[srow*40 + shalf*16];
    bf16_t* BsW = &Bs[srow*40 + shalf*16];

    for (int kc = 0; kc < K; kc += 32) {
        __syncthreads();
        uint4 b0 = *(const uint4*)(Bg + kc);
        uint4 b1 = *(const uint4*)(Bg + kc + 8);
        if (A32) {
            float4 f0 = *(const float4*)(Ag32 + kc);
            float4 f1 = *(const float4*)(Ag32 + kc + 4);
            float4 f2 = *(const float4*)(Ag32 + kc + 8);
            float4 f3 = *(const float4*)(Ag32 + kc + 12);
            v8bf u0, u1;
            u0[0]=(bf16_t)f0.x; u0[1]=(bf16_t)f0.y; u0[2]=(bf16_t)f0.z; u0[3]=(bf16_t)f0.w;
            u0[4]=(bf16_t)f1.x; u0[5]=(bf16_t)f1.y; u0[6]=(bf16_t)f1.z; u0[7]=(bf16_t)f1.w;
            u1[0]=(bf16_t)f2.x; u1[1]=(bf16_t)f2.y; u1[2]=(bf16_t)f2.z; u1[3]=(bf16_t)f2.w;
            u1[4]=(bf16_t)f3.x; u1[5]=(bf16_t)f3.y; u1[6]=(bf16_t)f3.z; u1[7]=(bf16_t)f3.w;
            *(v8bf*)AsW = u0; *(v8bf*)(AsW+8) = u1;
        } else {
            uint4 a0 = *(const uint4*)(Ag + kc);
            uint4 a1 = *(const uint4*)(Ag + kc + 8);
            *(uint4*)AsW = a0; *(uint4*)(AsW+8) = a1;
        }
        *(uint4*)BsW = b0; *(uint4*)(BsW+8) = b1;
        __syncthreads();
        v8bf af[4], bb[4];
#pragma unroll
        for (int i=0;i<4;i++) {
            af[i] = *(const v8bf*)&As[(wm*64 + i*16 + l16)*40 + quad*8];
            bb[i] = *(const v8bf*)&Bs[(wn*64 + i*16 + l16)*40 + quad*8];
        }
#pragma unroll
        for (int i=0;i<4;i++)
#pragma unroll
            for (int j=0;j<4;j++)
                acc[i][j] = __builtin_amdgcn_mfma_f32_16x16x32_bf16(af[i], bb[j], acc[i][j], 0,0,0);
    }

#pragma unroll
    for (int i=0;i<4;i++) {
#pragma unroll
        for (int j=0;j<4;j++) {
#pragma unroll
            for (int r=0;r<4;r++) {
                const int gr = m0 + wm*64 + i*16 + quad*4 + r;   // C/D row = quad*4+reg
                const int gc = n0 + wn*64 + j*16 + l16;          // C/D col = lane&15
                const float v = acc[i][j][r];
                if (mode == 0)      outF[(size_t)gr*N + gc] = v + bias0[gc] + bias1[gc];
                else if (mode == 1) outB[(size_t)gr*N + gc] = (bf16_t)fast_tanh(v);
                else if (mode == 2) outB[(size_t)gr*N + gc] = (bf16_t)v;
                else if (mode == 4) outF[(size_t)gr*N + (gc & 255)*4 + (gc >> 8)] = v + bias0[gc] + bias1[gc];
            }
        }
    }
}

// combined xg (mode 4, 24 tiles) + ke (mode 2, 100 tiles) + wproj/wad LDS-tiled
// transposes (64 tiles) — all depend only on k_prep / raw inputs.
__global__ __launch_bounds__(256) void k_gemm2(
    const bf16_t* __restrict__ embA, const bf16_t* __restrict__ wih,
    float* __restrict__ xg, const float* __restrict__ b_ih, const float* __restrict__ b_hh,
    const bf16_t* __restrict__ heA, const bf16_t* __restrict__ waeB, bf16_t* __restrict__ keB,
    const float* __restrict__ Wproj, bf16_t* __restrict__ wprojT,
    const float* __restrict__ Wad, bf16_t* __restrict__ wadT)
{
    __shared__ __align__(16) char shb[20480];
    const int bid = blockIdx.x;
    if (bid < 24) {
        gemm_tile(threadIdx.x, (bf16_t*)shb, (bf16_t*)(shb + 10240), embA, nullptr, wih,
                  bid, 1024, 256, 8, 4, xg, nullptr, b_ih, b_hh);
        return;
    }
    if (bid < 124) {
        gemm_tile(threadIdx.x, (bf16_t*)shb, (bf16_t*)(shb + 10240), heA, nullptr, waeB,
                  bid - 24, 256, 256, 2, 2, nullptr, keB, nullptr, nullptr);
        return;
    }
    float* tl = (float*)shb;   // 64*65*4 = 16640 B
    if (bid < 172) { transpose_tile(threadIdx.x, tl, Wproj, wprojT, 256, 768, bid - 124); return; }
    transpose_tile(threadIdx.x, tl, Wad, wadT, 256, 256, bid - 172);
}

// ---------------- dedicated logits GEMM: exp(feat@wout^T + b_out), rsum -------
// M=384, N=32000, K=768. BK=64, pitch-72 LDS. mode-3 epilogue.
__global__ __launch_bounds__(256) void k_gemm3(
    const bf16_t* __restrict__ A, const bf16_t* __restrict__ B,
    float* __restrict__ outF, const float* __restrict__ bias0,
    const int* __restrict__ padp, float* __restrict__ rsum)
{
    __shared__ bf16_t As[128*72];
    __shared__ bf16_t Bs[128*72];
    const int tid = threadIdx.x;
    const int mt = blockIdx.x / 250, nt = blockIdx.x % 250;
    const int m0 = mt*128, n0 = nt*128;
    const int lane = tid & 63, wave = tid >> 6;
    const int wm = wave >> 1, wn = wave & 1;
    const int quad = lane >> 4, l16 = lane & 15;

    v4f acc[4][4];
#pragma unroll
    for (int i=0;i<4;i++)
#pragma unroll
        for (int j=0;j<4;j++) acc[i][j] = (v4f){0.f,0.f,0.f,0.f};

    const int srow = tid >> 1, shalf = tid & 1;       // 2 threads/row, 64B each
    const bf16_t* Ag = A + (size_t)(m0+srow)*768 + shalf*32;
    const bf16_t* Bg = B + (size_t)(n0+srow)*768 + shalf*32;
    bf16_t* AsW = &As[srow*72 + shalf*32];
    bf16_t* BsW = &Bs[srow*72 + shalf*32];

    for (int kc = 0; kc < 768; kc += 64) {
        __syncthreads();
        uint4 a0 = *(const uint4*)(Ag + kc);
        uint4 a1 = *(const uint4*)(Ag + kc + 8);
        uint4 a2 = *(const uint4*)(Ag + kc + 16);
        uint4 a3 = *(const uint4*)(Ag + kc + 24);
        uint4 b0 = *(const uint4*)(Bg + kc);
        uint4 b1 = *(const uint4*)(Bg + kc + 8);
        uint4 b2 = *(const uint4*)(Bg + kc + 16);
        uint4 b3 = *(const uint4*)(Bg + kc + 24);
        *(uint4*)(AsW)    = a0; *(uint4*)(AsW+8)  = a1;
        *(uint4*)(AsW+16) = a2; *(uint4*)(AsW+24) = a3;
        *(uint4*)(BsW)    = b0; *(uint4*)(BsW+8)  = b1;
        *(uint4*)(BsW+16) = b2; *(uint4*)(BsW+24) = b3;
        __syncthreads();
#pragma unroll
        for (int kk = 0; kk < 2; ++kk) {
            v8bf af[4], bb[4];
#pragma unroll
            for (int i=0;i<4;i++) {
                af[i] = *(const v8bf*)&As[(wm*64 + i*16 + l16)*72 + kk*32 + quad*8];
                bb[i] = *(const v8bf*)&Bs[(wn*64 + i*16 + l16)*72 + kk*32 + quad*8];
            }
#pragma unroll
            for (int i=0;i<4;i++)
#pragma unroll
                for (int j=0;j<4;j++)
                    acc[i][j] = __builtin_amdgcn_mfma_f32_16x16x32_bf16(af[i], bb[j], acc[i][j], 0,0,0);
        }
    }

    const int pad = *padp;
    float* rs = (float*)As;          // LDS reuse for row partial sums
    __syncthreads();
    if (tid < 128) rs[tid] = 0.f;
    __syncthreads();
#pragma unroll
    for (int i=0;i<4;i++) {
        float rloc[4] = {0.f,0.f,0.f,0.f};
#pragma unroll
        for (int j=0;j<4;j++) {
#pragma unroll
            for (int r=0;r<4;r++) {
                const int gr = m0 + wm*64 + i*16 + quad*4 + r;
                const int gc = n0 + wn*64 + j*16 + l16;
                const float ex = (gc == pad) ? 0.f : __expf(acc[i][j][r] + bias0[gc]);
                outF[(size_t)gr*VOCABN + gc] = ex;
                rloc[r] += ex;
            }
        }
#pragma unroll
        for (int r=0;r<4;r++)
            atomicAdd(&rs[wm*64 + i*16 + quad*4 + r], rloc[r]);
    }
    __syncthreads();
    if (tid < 128) atomicAdd(&rsum[m0 + tid], rs[tid]);
}

// ---------------- device-scope grid barrier (monotonic counter) ----------------
__device__ __forceinline__ void gridbar(int* bar, int target) {
    __syncthreads();
    if (threadIdx.x == 0) {
        __threadfence();   // release: publish this block's h stores device-wide
        __hip_atomic_fetch_add(bar, 1, __ATOMIC_ACQ_REL, __HIP_MEMORY_SCOPE_AGENT);
        while (__hip_atomic_load(bar, __ATOMIC_ACQUIRE, __HIP_MEMORY_SCOPE_AGENT) < target) { }
        __threadfence();   // acquire: invalidate stale L1/L2 before h reads
    }
    __syncthreads();
}

// ---------------- sequential LSTM chain: 4 cooperating CUs, reg-resident W_hh --
// R9 form (141us): R5 structure with loop stores moved off the L2 (packed h via
// relaxed agent-scope atomic store; hallF deferred+atomic; hallB eliminated).
__global__ __launch_bounds__(512, 2) void k_lstm(
    const bf16_t* __restrict__ Whh, const float* __restrict__ xgT,
    const float* __restrict__ c0,
    u32* __restrict__ hpk,           // [16][256] packed (hi | lo<<16)
    float* __restrict__ hallF,
    int* __restrict__ bar)
{
    __shared__ float gl[16][260];   // pre-activation exchange, padded

    const int tid = threadIdx.x;
    const int k = blockIdx.x;            // d-slice owner
    const int w = tid >> 6, lane = tid & 63;
    const int l16 = lane & 15, quad = lane >> 4;

    // B-fragments: wave w owns CU-local cols c in [w*32, w*32+32), ct in {0,1}
    v8bf wb[2][8];
#pragma unroll
    for (int ct = 0; ct < 2; ++ct) {
        const int c = w*32 + ct*16 + l16;
        const int row = (c >> 6)*256 + k*64 + (c & 63);
#pragma unroll
        for (int kc = 0; kc < 8; ++kc)
            wb[ct][kc] = *(const v8bf*)&Whh[(size_t)row*DIM + kc*32 + quad*8];
    }

    float cst[2];
#pragma unroll
    for (int e = 0; e < 2; ++e) {
        const int li = tid + e*512;
        cst[e] = c0[(li >> 6)*DIM + k*64 + (li & 63)];
    }

    for (int step = 0; step < TGT; ++step) {
        // packed h loads (plain cached; gridbar's inv guarantees freshness)
        uint4 pq[8][2];
#pragma unroll
        for (int kc = 0; kc < 8; ++kc) {
            const uint4* pp = (const uint4*)&hpk[l16*DIM + kc*32 + quad*8];
            pq[kc][0] = pp[0]; pq[kc][1] = pp[1];
        }
        // xv: 4 gates of xg for the two owned elements (float4, coalesced)
        float4 xv[2];
#pragma unroll
        for (int e = 0; e < 2; ++e) {
            const int li = tid + e*512;
            const int b = li >> 6, dd = li & 63;
            xv[e] = *(const float4*)&xgT[((size_t)(step*BS + b)*DIM + k*64 + dd)*4];
        }
        // unpack hi/lo
        v8bf ahi[8], alo[8];
#pragma unroll
        for (int kc = 0; kc < 8; ++kc) {
            const u32 uu[8] = {pq[kc][0].x, pq[kc][0].y, pq[kc][0].z, pq[kc][0].w,
                               pq[kc][1].x, pq[kc][1].y, pq[kc][1].z, pq[kc][1].w};
#pragma unroll
            for (int j = 0; j < 8; ++j) {
                union { u32 u; u16 s[2]; } x; x.u = uu[j];
                ahi[kc][j] = *(const bf16_t*)&x.s[0];
                alo[kc][j] = *(const bf16_t*)&x.s[1];
            }
        }

        v4f acc[2] = {(v4f){0.f,0.f,0.f,0.f}, (v4f){0.f,0.f,0.f,0.f}};
#pragma unroll
        for (int kc = 0; kc < 8; ++kc)
#pragma unroll
            for (int ct = 0; ct < 2; ++ct) {
                acc[ct] = __builtin_amdgcn_mfma_f32_16x16x32_bf16(ahi[kc], wb[ct][kc], acc[ct], 0,0,0);
                acc[ct] = __builtin_amdgcn_mfma_f32_16x16x32_bf16(alo[kc], wb[ct][kc], acc[ct], 0,0,0);
            }
        // exchange pre-activations: C row = quad*4+r (b), col = l16 (c-in-tile)
#pragma unroll
        for (int ct = 0; ct < 2; ++ct) {
            const int c = w*32 + ct*16 + l16;
#pragma unroll
            for (int r = 0; r < 4; ++r)
                gl[quad*4 + r][c] = acc[ct][r];
        }
        __syncthreads();
        // elementwise: thread owns (b, dd) and (b+8, dd)
        float hnv[2];
#pragma unroll
        for (int e = 0; e < 2; ++e) {
            const int li = tid + e*512;
            const int b = li >> 6, dd = li & 63;
            const int d = k*64 + dd;
            const float gi = gl[b][dd]        + xv[e].x;
            const float gf = gl[b][64 + dd]   + xv[e].y;
            const float gg = gl[b][128 + dd]  + xv[e].z;
            const float go = gl[b][192 + dd]  + xv[e].w;
            const float si = 1.f/(1.f+__expf(-gi));
            const float sf = 1.f/(1.f+__expf(-gf));
            const float so = 1.f/(1.f+__expf(-go));
            const float cn = sf*cst[e] + si*fast_tanh(gg);
            const float hn = so*fast_tanh(cn);
            cst[e] = cn;
            hnv[e] = hn;
            const bf16_t hi = (bf16_t)hn;
            const bf16_t lo = (bf16_t)(hn - (float)hi);
            const u32 pk = (u32)(*(const u16*)&hi) | ((u32)(*(const u16*)&lo) << 16);
            __hip_atomic_store(&hpk[b*DIM + d], pk, __ATOMIC_RELAXED, __HIP_MEMORY_SCOPE_AGENT);
        }
        if (step < TGT-1) gridbar(bar, (step+1)*LSTM_NBLK);
        // deferred hallF stores: coherence-point writes, off the drain path
#pragma unroll
        for (int e = 0; e < 2; ++e) {
            const int li = tid + e*512;
            const int b = li >> 6, dd = li & 63;
            const int d = k*64 + dd;
            union { float f; u32 u; } cv; cv.f = hnv[e];
            __hip_atomic_store((u32*)&hallF[(size_t)(step*BS + b)*DIM + d], cv.u,
                               __ATOMIC_RELAXED, __HIP_MEMORY_SCOPE_AGENT);
        }
    }
}

// ---------------- expE[t,b,s] = exp(ke[s,b,:] . h[t,b,:]) (device body) --------
__device__ __forceinline__ void escore_body(const int blk, const int tid, float* hS,
    const bf16_t* __restrict__ ke, const float* __restrict__ hallF, float* __restrict__ expE)
{
    const int t = blk >> 4, b = blk & 15;
    hS[tid] = hallF[(size_t)(t*BS + b)*DIM + tid];
    __syncthreads();
    for (int s = tid; s < SRC; s += 256) {
        const v8bf* kp = (const v8bf*)(ke + ((size_t)s*BS + b)*DIM);
        float e = 0.f;
#pragma unroll 8
        for (int m=0;m<32;m++) {
            v8bf kv = kp[m];
#pragma unroll
            for (int i=0;i<8;i++) e += (float)kv[i]*hS[m*8+i];
        }
        expE[((size_t)t*BS + b)*SRC + s] = __expf(e);
    }
}

// fused escore + qd GEMM (qd = h_all @ W_attn_dec, 6 tiles, A32 from hallF)
__global__ __launch_bounds__(256) void k_esq(
    const bf16_t* __restrict__ ke, const float* __restrict__ hallF, float* __restrict__ expE,
    const bf16_t* __restrict__ wadT, bf16_t* __restrict__ qdG)
{
    __shared__ __align__(16) char shb[20480];
    if (blockIdx.x < NROW) {
        escore_body(blockIdx.x, threadIdx.x, (float*)shb, ke, hallF, expE);
        return;
    }
    gemm_tile(threadIdx.x, (bf16_t*)shb, (bf16_t*)(shb + 10240), nullptr, hallF, wadT,
              blockIdx.x - NROW, 256, 256, 2, 2, nullptr, qdG, nullptr, nullptr);
}

// ---------------- in-place inclusive cumulative sum of expE over t ------------
__global__ __launch_bounds__(256) void k_prefix(float* __restrict__ expE)
{
    const int i = blockIdx.x*256 + threadIdx.x;   // flat (b,s)
    if (i >= BS*SRC) return;
    const int b = i / SRC, s = i % SRC;
    float c = 0.f;
    for (int t = 0; t < TGT; ++t) {
        const size_t idx = ((size_t)t*BS + b)*SRC + s;
        c += expE[idx];
        expE[idx] = c;
    }
}

// ---------------- per-(t,b) attention tail (device body) ----------------
// cumE is the CUMULATIVE expE: my = cum[t]-cum[t-1], prev-sum = cum[t-1].
// ce reads he_bf [s][b][d] DIRECTLY (coalesced across threads: consecutive
// tid = consecutive d) — the stride-16KB heT transpose is eliminated.
__device__ void attn_body(char* sh, const int blk, const int tid,
    const float* __restrict__ cumE, const bf16_t* __restrict__ heA,
    const float* __restrict__ hallF, const bf16_t* __restrict__ qdG,
    const float* __restrict__ wu, const float* __restrict__ bu,
    bf16_t* __restrict__ feat, float* __restrict__ Ae, float* __restrict__ ps)
{
    float* hS   = (float*)sh;        // 256
    float* qdS  = hS + 256;          // 256
    float* eeS  = qdS + 256;         // 400
    float* adS  = eeS + 400;         // 24
    float* red  = adS + 24;          // 4
    float* misc = red + 4;           // 2
    const int t = blk >> 4, b = blk & 15;

    hS[tid]  = hallF[(size_t)(t*BS + b)*DIM + tid];
    qdS[tid] = (float)qdG[(size_t)(t*BS + b)*DIM + tid];
    __syncthreads();

    for (int s = tid; s < SRC; s += 256) {
        if (t == 0) {
            eeS[s] = cumE[(size_t)b*SRC + s];               // cum[0] == raw expE
        } else {
            const float prev = cumE[((size_t)(t-1)*BS + b)*SRC + s];
            const float cur  = cumE[((size_t)t*BS + b)*SRC + s];
            eeS[s] = (cur - prev) / prev;
        }
    }
    __syncthreads();
    {   // esum
        float pa = 0.f;
        for (int s = tid; s < SRC; s += 256) pa += eeS[s];
#pragma unroll
        for (int o=32;o>0;o>>=1) pa += __shfl_down(pa, o);
        if ((tid & 63) == 0) red[tid>>6] = pa;
        __syncthreads();
        if (tid == 0) misc[0] = 1.f/(red[0]+red[1]+red[2]+red[3]);
        __syncthreads();
    }
    const float inv_es = misc[0];
    for (int s = tid; s < SRC; s += 256)
        Ae[((size_t)t*BS + b)*SRC + s] = eeS[s] * inv_es;

    float ce;
    {
        const bf16_t* hp = heA + (size_t)b*DIM + tid;   // he[s][b][d], s-stride BS*DIM
        float a0=0.f, a1=0.f, a2=0.f, a3=0.f;
        for (int s = 0; s < SRC; s += 4) {
            a0 += (float)hp[(size_t)(s+0)*BS*DIM] * eeS[s+0];
            a1 += (float)hp[(size_t)(s+1)*BS*DIM] * eeS[s+1];
            a2 += (float)hp[(size_t)(s+2)*BS*DIM] * eeS[s+2];
            a3 += (float)hp[(size_t)(s+3)*BS*DIM] * eeS[s+3];
        }
        ce = ((a0+a1)+(a2+a3)) * inv_es;
    }

    {
        const int wv = tid >> 6, ln = tid & 63;
        for (int tau = wv; tau <= t; tau += 4) {
            float4 a = *(const float4*)(hallF + ((size_t)(tau*BS + b))*DIM + ln*4);
            float e = a.x*qdS[ln*4] + a.y*qdS[ln*4+1] + a.z*qdS[ln*4+2] + a.w*qdS[ln*4+3];
#pragma unroll
            for (int o=32;o>0;o>>=1) e += __shfl_down(e, o);
            if (ln == 0) adS[tau] = __expf(e);
        }
    }
    __syncthreads();
    if (tid < 64) {
        float v = (tid <= t) ? adS[tid] : 0.f;
#pragma unroll
        for (int o=32;o>0;o>>=1) v += __shfl_down(v, o);
        if (tid == 0) misc[1] = 1.f/v;
    }
    __syncthreads();
    float cd = 0.f;
    for (int tau = 0; tau <= t; ++tau)
        cd += adS[tau] * hallF[((size_t)(tau*BS + b))*DIM + tid];
    cd *= misc[1];
    if (t == 0) cd = 0.f;

    const float hd = hS[tid];
    const size_t fr = ((size_t)t*BS + b)*768;
    feat[fr + tid]       = (bf16_t)hd;
    feat[fr + 256 + tid] = (bf16_t)ce;
    feat[fr + 512 + tid] = (bf16_t)cd;
    float pw = hd*wu[tid] + ce*wu[256 + tid] + cd*wu[512 + tid];
#pragma unroll
    for (int o=32;o>0;o>>=1) pw += __shfl_down(pw, o);
    if ((tid & 63) == 0) red[tid>>6] = pw;
    __syncthreads();
    if (tid == 0) {
        float s = red[0]+red[1]+red[2]+red[3];
        ps[t*BS + b] = 1.f/(1.f+__expf(-(s + bu[0])));
    }
}

// ---------------- fused: attention tail (blocks 0-383) + W_out tiles (384-1883) -
__global__ __launch_bounds__(256) void k_attnw(
    const float* __restrict__ cumE, const bf16_t* __restrict__ heA,
    const float* __restrict__ hallF, const bf16_t* __restrict__ qdG,
    const float* __restrict__ wu, const float* __restrict__ bu,
    bf16_t* __restrict__ feat, float* __restrict__ Ae, float* __restrict__ ps,
    const float* __restrict__ Wemb, const bf16_t* __restrict__ wprojT,
    bf16_t* __restrict__ woutB)
{
    __shared__ __align__(16) char shb[20480];
    if (blockIdx.x < NROW) {
        attn_body(shb, blockIdx.x, threadIdx.x, cumE, heA, hallF, qdG, wu, bu, feat, Ae, ps);
        return;
    }
    gemm_tile(threadIdx.x, (bf16_t*)shb, (bf16_t*)(shb + 10240), nullptr, Wemb, wprojT,
              blockIdx.x - NROW, 768, 256, 6, 1,
              nullptr, woutB, nullptr, nullptr);
}

// ---------------- final: scale row by ps[r]/rsum[r], then copy-scatter ---------
__global__ __launch_bounds__(256) void k_final(
    float* __restrict__ out, const float* __restrict__ rsum,
    const float* __restrict__ ps, const int* __restrict__ src,
    const float* __restrict__ Ae)
{
    const int r = blockIdx.x;        // r = t*BS + b
    const int b = r & (BS-1);
    const float p  = ps[r];
    const float sc = p / rsum[r];
    float4* o4 = (float4*)(out + (size_t)r*VOCABN);
    for (int i = threadIdx.x; i < VOCABN/4; i += 256) {
        float4 v = o4[i];
        v.x*=sc; v.y*=sc; v.z*=sc; v.w*=sc;
        o4[i] = v;
    }
    __syncthreads();   // row fully scaled before scatter into it
    for (int s = threadIdx.x; s < SRC; s += 256) {
        const int v = src[s*BS + b];
        atomicAdd(&out[(size_t)r*VOCABN + v], Ae[(size_t)r*SRC + s] * p);
    }
}

// ---------------- workspace layout (bytes, 16B-aligned) ----------------
#define O_WHH    0u
#define O_WADT   524288u
#define O_HEBF   655360u
#define O_KE     7208960u
#define O_WAE    10485760u
#define O_WPROJT 10616832u
#define O_WIH    11010048u
#define O_EMBA   11534336u
#define O_WOUT   11730944u
#define O_XG     60882944u
#define O_HALLF  62455808u
#define O_QD     63045632u
#define O_EXPE   63242240u   // first 16 KB double as hpk (packed h) during k_lstm
#define O_FEAT   63856640u
#define O_AE     64446464u
#define O_PS     65060864u
#define O_BAR    65062400u   // barrier counter + rsum, zeroed by k_prep each call
#define O_RSUM   65063936u

extern "C" void kernel_launch(void* const* d_in, const int* in_sizes, int n_in,
                              void* d_out, int out_size, void* d_ws, size_t ws_size,
                              hipStream_t stream)
{
    const int*   inputs = (const int*)  d_in[0];
    const int*   src    = (const int*)  d_in[1];
    const float* h_e    = (const float*)d_in[2];
    const float* h0     = (const float*)d_in[3];
    const float* c0     = (const float*)d_in[4];
    const float* W_emb  = (const float*)d_in[5];
    const float* W_ih   = (const float*)d_in[6];
    const float* b_ih   = (const float*)d_in[7];
    const float* W_hh   = (const float*)d_in[8];
    const float* b_hh   = (const float*)d_in[9];
    const float* W_ae   = (const float*)d_in[10];
    const float* W_ad   = (const float*)d_in[11];
    const float* W_proj = (const float*)d_in[12];
    const float* W_u    = (const float*)d_in[13];
    const float* b_u    = (const float*)d_in[14];
    const float* b_out  = (const float*)d_in[15];
    const int*   pad_id = (const int*)  d_in[16];

    char* w = (char*)d_ws;
    bf16_t* whh_bf  = (bf16_t*)(w + O_WHH);
    bf16_t* wadT_bf = (bf16_t*)(w + O_WADT);
    bf16_t* he_bf   = (bf16_t*)(w + O_HEBF);
    bf16_t* ke_bf   = (bf16_t*)(w + O_KE);
    bf16_t* wae_bf  = (bf16_t*)(w + O_WAE);
    bf16_t* wprojT  = (bf16_t*)(w + O_WPROJT);
    bf16_t* wih_bf  = (bf16_t*)(w + O_WIH);
    bf16_t* embA_bf = (bf16_t*)(w + O_EMBA);
    bf16_t* wout_bf = (bf16_t*)(w + O_WOUT);
    float*  xg      = (float*) (w + O_XG);      // holds xgT: [row][d][gate]
    float*  hallF   = (float*) (w + O_HALLF);
    bf16_t* qdG     = (bf16_t*)(w + O_QD);
    float*  expE    = (float*) (w + O_EXPE);
    u32*    hpk     = (u32*)   (w + O_EXPE);          // 16 KB, dead until k_esq
    bf16_t* feat_bf = (bf16_t*)(w + O_FEAT);
    float*  Ae      = (float*) (w + O_AE);
    float*  ps      = (float*) (w + O_PS);
    int*    bar     = (int*)   (w + O_BAR);
    u32*    zeroreg = (u32*)   (w + O_BAR);           // bar + rsum, 3072 B
    float*  rsum    = (float*) (w + O_RSUM);
    float*  out     = (float*)d_out;

    // prep: coalesced conversions only (+ zeroes bar/rsum, packs h0)
    k_prep<<<1024, 256, 0, stream>>>(W_hh, h_e, W_emb, W_ae, W_ih, inputs, h0,
                                     whh_bf, he_bf, wae_bf, wih_bf,
                                     embA_bf, hpk, zeroreg);
    // xgT (24 tiles) + ke (100 tiles) + wproj/wad LDS-tiled transposes (64)
    k_gemm2<<<188, 256, 0, stream>>>(embA_bf, wih_bf, xg, b_ih, b_hh,
                                     he_bf, wae_bf, ke_bf,
                                     W_proj, wprojT, W_ad, wadT_bf);
    // cooperative 4-CU LSTM chain, register-resident W_hh, L2-clean writes
    k_lstm<<<LSTM_NBLK, 512, 0, stream>>>(whh_bf, xg, c0, hpk, hallF, bar);
    // fused escore (blocks 0-383) + qd GEMM (blocks 384-389, A32 from hallF)
    k_esq<<<NROW + 6, 256, 0, stream>>>(ke_bf, hallF, expE, wadT_bf, qdG);
    // in-place cumulative sum of expE over t (25 blocks)
    k_prefix<<<25, 256, 0, stream>>>(expE);
    // fused attention tail (0-383) + W_out GEMM (384-1883)
    k_attnw<<<NROW + 1500, 256, 0, stream>>>(expE, he_bf, hallF, qdG, W_u, b_u,
                                             feat_bf, Ae, ps,
                                             W_emb, wprojT, wout_bf);
    // exp(logits + b_out), pad -> 0, + fused row sums  (M=384, N=32000, K=768)
    k_gemm3<<<750, 256, 0, stream>>>(feat_bf, wout_bf, out, b_out, pad_id, rsum);
    // scale + copy-scatter, one block per row
    k_final<<<NROW, 256, 0, stream>>>(out, rsum, ps, src, Ae);
}

// Round 11
// 406.460 us; speedup vs baseline: 1.0820x; 1.0192x over previous
//
#include <hip/hip_runtime.h>
#include <cstdint>
#include <cstddef>

// ---------------- problem constants ----------------
#define TGT   24
#define BS    16
#define SRC   400
#define VOCABN 32000
#define DIM   256
#define NROW  (TGT*BS)   // 384
#define LSTM_NBLK 4

typedef __bf16 bf16_t;
typedef __bf16 v8bf __attribute__((ext_vector_type(8)));
typedef float  v4f  __attribute__((ext_vector_type(4)));
typedef unsigned int u32;
typedef unsigned short u16;

__device__ __forceinline__ float fast_tanh(float x) {
    // monotone, no NaN for large |x|: e->0 => -1, e->inf => +1
    float e = __expf(2.f*x);
    return 1.f - 2.f/(e + 1.f);
}

// ---------------- prep: dtype conversions / gather (coalesced only) -----------
// Scattered transposes (heT/wprojT/wadT) moved out: heT is ELIMINATED (attn
// reads he_bf directly, coalesced), wprojT/wadT are LDS-tiled transposes in
// k_gemm2. Also zeroes bar+rsum and packs h0.
__global__ void k_prep(const float* __restrict__ Whh, const float* __restrict__ he,
                       const float* __restrict__ Wemb, const float* __restrict__ Wae,
                       const float* __restrict__ Wih, const int* __restrict__ inputs,
                       const float* __restrict__ h0,
                       bf16_t* o_whh, bf16_t* o_he, bf16_t* o_wae, bf16_t* o_wih,
                       bf16_t* o_embA, u32* o_hpk, u32* o_zero)
{
    const long S0=262144, S1=1638400, S2=65536, S3=262144, S4=98304, S5=4096, S6=768;
    const long total = S0+S1+S2+S3+S4+S5+S6;
    for (long i = (long)blockIdx.x*blockDim.x + threadIdx.x; i < total;
         i += (long)gridDim.x*blockDim.x) {
        long j = i;
        if (j < S0) { o_whh[j] = (bf16_t)Whh[j]; continue; }           j -= S0;
        if (j < S1) { o_he[j] = (bf16_t)he[j]; continue; }             j -= S1;
        if (j < S2) { o_wae[j] = (bf16_t)Wae[j]; continue; }           j -= S2;
        if (j < S3) { o_wih[j] = (bf16_t)Wih[j]; continue; }           j -= S3;
        if (j < S4) { long r = j>>8, k = j&255; o_embA[j] = (bf16_t)Wemb[(long)inputs[r]*DIM + k]; continue; } j -= S4;
        if (j < S5) { // h0 -> packed (hi | lo<<16), [16][256]
            float v = h0[j];
            bf16_t hi = (bf16_t)v;
            bf16_t lo = (bf16_t)(v - (float)hi);
            o_hpk[j] = (u32)(*(const u16*)&hi) | ((u32)(*(const u16*)&lo) << 16);
            continue; }                                                j -= S5;
        o_zero[j] = 0;   // barrier counter + rsum region (3072 B)
    }
}

// ---------------- LDS-tiled fp32 -> bf16 transpose (64x64 tiles) --------------
// out[c][r] = (bf16)in[r][c]. Coalesced loads (float4 rows), 64x65 LDS tile
// (2-way-max bank aliasing = free), coalesced 32B bf16 stores.
__device__ void transpose_tile(const int tid, float* lds /* 64*65 floats */,
                               const float* __restrict__ in, bf16_t* __restrict__ out,
                               const int R, const int C, const int tileIdx)
{
    const int tilesC = C >> 6;
    const int tr = (tileIdx / tilesC) << 6;
    const int tc = (tileIdx % tilesC) << 6;
    const int r0 = tid >> 4;            // 0..15
    const int c0 = (tid & 15) * 4;      // 4 floats/thread
#pragma unroll
    for (int p = 0; p < 4; ++p) {
        const int r = p*16 + r0;
        float4 v = *(const float4*)&in[(size_t)(tr + r)*C + tc + c0];
        lds[r*65 + c0+0] = v.x; lds[r*65 + c0+1] = v.y;
        lds[r*65 + c0+2] = v.z; lds[r*65 + c0+3] = v.w;
    }
    __syncthreads();
    const int oc  = tid >> 2;           // 0..63: output row (col of in)
    const int orr = (tid & 3) * 16;     // 16 elems along r
    bf16_t tmp[16];
#pragma unroll
    for (int k = 0; k < 16; ++k)
        tmp[k] = (bf16_t)lds[(orr + k)*65 + oc];
    bf16_t* op = &out[(size_t)(tc + oc)*R + tr + orr];
    *(uint4*)op       = ((uint4*)tmp)[0];
    *(uint4*)(op + 8) = ((uint4*)tmp)[1];
}

// ---------------- generic bf16 MFMA GEMM tile, 128x128, BK=32 (device body) ----
// C[M,N] = A[M,K] @ B[N,K]^T  (row-major, K-contiguous). A32!=null: A read fp32.
// mode 0: fp32 out + bias0 + bias1
// mode 1: bf16 out, tanh
// mode 2: bf16 out
// mode 4: fp32 out + bias0 + bias1, written TRANSPOSED-per-gate for the LSTM:
//         out[row*1024 + (col&255)*4 + (col>>8)]   (N must be 1024)
__device__ __forceinline__ void gemm_tile(
    const int tid, bf16_t* As, bf16_t* Bs,
    const bf16_t* __restrict__ A, const float* __restrict__ A32,
    const bf16_t* __restrict__ B,
    const int tileIdx, const int N, const int K, const int Ntiles, const int mode,
    float* __restrict__ outF, bf16_t* __restrict__ outB,
    const float* __restrict__ bias0, const float* __restrict__ bias1)
{
    const int mt   = tileIdx / Ntiles, nt = tileIdx % Ntiles;
    const int m0   = mt*128, n0 = nt*128;
    const int lane = tid & 63, wave = tid >> 6;
    const int wm   = wave >> 1, wn = wave & 1;
    const int quad = lane >> 4, l16 = lane & 15;

    v4f acc[4][4];
#pragma unroll
    for (int i=0;i<4;i++)
#pragma unroll
        for (int j=0;j<4;j++) acc[i][j] = (v4f){0.f,0.f,0.f,0.f};

    const int srow = tid >> 1, shalf = tid & 1;       // staging: 2 threads/row
    const bf16_t* Ag   = A   ? A   + (size_t)(m0+srow)*K + shalf*16 : nullptr;
    const float*  Ag32 = A32 ? A32 + (size_t)(m0+srow)*K + shalf*16 : nullptr;
    const bf16_t* Bg = B + (size_t)(n0+srow)*K + shalf*16;
    bf16_t* AsW = &As[srow*40 + shalf*16];
    bf16_t* BsW = &Bs[srow*40 + shalf*16];

    for (int kc = 0; kc < K; kc += 32) {
        __syncthreads();
        uint4 b0 = *(const uint4*)(Bg + kc);
        uint4 b1 = *(const uint4*)(Bg + kc + 8);
        if (A32) {
            float4 f0 = *(const float4*)(Ag32 + kc);
            float4 f1 = *(const float4*)(Ag32 + kc + 4);
            float4 f2 = *(const float4*)(Ag32 + kc + 8);
            float4 f3 = *(const float4*)(Ag32 + kc + 12);
            v8bf u0, u1;
            u0[0]=(bf16_t)f0.x; u0[1]=(bf16_t)f0.y; u0[2]=(bf16_t)f0.z; u0[3]=(bf16_t)f0.w;
            u0[4]=(bf16_t)f1.x; u0[5]=(bf16_t)f1.y; u0[6]=(bf16_t)f1.z; u0[7]=(bf16_t)f1.w;
            u1[0]=(bf16_t)f2.x; u1[1]=(bf16_t)f2.y; u1[2]=(bf16_t)f2.z; u1[3]=(bf16_t)f2.w;
            u1[4]=(bf16_t)f3.x; u1[5]=(bf16_t)f3.y; u1[6]=(bf16_t)f3.z; u1[7]=(bf16_t)f3.w;
            *(v8bf*)AsW = u0; *(v8bf*)(AsW+8) = u1;
        } else {
            uint4 a0 = *(const uint4*)(Ag + kc);
            uint4 a1 = *(const uint4*)(Ag + kc + 8);
            *(uint4*)AsW = a0; *(uint4*)(AsW+8) = a1;
        }
        *(uint4*)BsW = b0; *(uint4*)(BsW+8) = b1;
        __syncthreads();
        v8bf af[4], bb[4];
#pragma unroll
        for (int i=0;i<4;i++) {
            af[i] = *(const v8bf*)&As[(wm*64 + i*16 + l16)*40 + quad*8];
            bb[i] = *(const v8bf*)&Bs[(wn*64 + i*16 + l16)*40 + quad*8];
        }
#pragma unroll
        for (int i=0;i<4;i++)
#pragma unroll
            for (int j=0;j<4;j++)
                acc[i][j] = __builtin_amdgcn_mfma_f32_16x16x32_bf16(af[i], bb[j], acc[i][j], 0,0,0);
    }

#pragma unroll
    for (int i=0;i<4;i++) {
#pragma unroll
        for (int j=0;j<4;j++) {
#pragma unroll
            for (int r=0;r<4;r++) {
                const int gr = m0 + wm*64 + i*16 + quad*4 + r;   // C/D row = quad*4+reg
                const int gc = n0 + wn*64 + j*16 + l16;          // C/D col = lane&15
                const float v = acc[i][j][r];
                if (mode == 0)      outF[(size_t)gr*N + gc] = v + bias0[gc] + bias1[gc];
                else if (mode == 1) outB[(size_t)gr*N + gc] = (bf16_t)fast_tanh(v);
                else if (mode == 2) outB[(size_t)gr*N + gc] = (bf16_t)v;
                else if (mode == 4) outF[(size_t)gr*N + (gc & 255)*4 + (gc >> 8)] = v + bias0[gc] + bias1[gc];
            }
        }
    }
}

// combined xg (mode 4, 24 tiles) + ke (mode 2, 100 tiles) + wproj/wad LDS-tiled
// transposes (64 tiles) — all depend only on k_prep / raw inputs.
__global__ __launch_bounds__(256) void k_gemm2(
    const bf16_t* __restrict__ embA, const bf16_t* __restrict__ wih,
    float* __restrict__ xg, const float* __restrict__ b_ih, const float* __restrict__ b_hh,
    const bf16_t* __restrict__ heA, const bf16_t* __restrict__ waeB, bf16_t* __restrict__ keB,
    const float* __restrict__ Wproj, bf16_t* __restrict__ wprojT,
    const float* __restrict__ Wad, bf16_t* __restrict__ wadT)
{
    __shared__ __align__(16) char shb[20480];
    const int bid = blockIdx.x;
    if (bid < 24) {
        gemm_tile(threadIdx.x, (bf16_t*)shb, (bf16_t*)(shb + 10240), embA, nullptr, wih,
                  bid, 1024, 256, 8, 4, xg, nullptr, b_ih, b_hh);
        return;
    }
    if (bid < 124) {
        gemm_tile(threadIdx.x, (bf16_t*)shb, (bf16_t*)(shb + 10240), heA, nullptr, waeB,
                  bid - 24, 256, 256, 2, 2, nullptr, keB, nullptr, nullptr);
        return;
    }
    float* tl = (float*)shb;   // 64*65*4 = 16640 B
    if (bid < 172) { transpose_tile(threadIdx.x, tl, Wproj, wprojT, 256, 768, bid - 124); return; }
    transpose_tile(threadIdx.x, tl, Wad, wadT, 256, 256, bid - 172);
}

// ---------------- dedicated logits GEMM: exp(feat@wout^T + b_out), rsum -------
// M=384, N=32000, K=768. BK=64, pitch-72 LDS. mode-3 epilogue.
__global__ __launch_bounds__(256) void k_gemm3(
    const bf16_t* __restrict__ A, const bf16_t* __restrict__ B,
    float* __restrict__ outF, const float* __restrict__ bias0,
    const int* __restrict__ padp, float* __restrict__ rsum)
{
    __shared__ bf16_t As[128*72];
    __shared__ bf16_t Bs[128*72];
    const int tid = threadIdx.x;
    const int mt = blockIdx.x / 250, nt = blockIdx.x % 250;
    const int m0 = mt*128, n0 = nt*128;
    const int lane = tid & 63, wave = tid >> 6;
    const int wm = wave >> 1, wn = wave & 1;
    const int quad = lane >> 4, l16 = lane & 15;

    v4f acc[4][4];
#pragma unroll
    for (int i=0;i<4;i++)
#pragma unroll
        for (int j=0;j<4;j++) acc[i][j] = (v4f){0.f,0.f,0.f,0.f};

    const int srow = tid >> 1, shalf = tid & 1;       // 2 threads/row, 64B each
    const bf16_t* Ag = A + (size_t)(m0+srow)*768 + shalf*32;
    const bf16_t* Bg = B + (size_t)(n0+srow)*768 + shalf*32;
    bf16_t* AsW = &As[srow*72 + shalf*32];
    bf16_t* BsW = &Bs[srow*72 + shalf*32];

    for (int kc = 0; kc < 768; kc += 64) {
        __syncthreads();
        uint4 a0 = *(const uint4*)(Ag + kc);
        uint4 a1 = *(const uint4*)(Ag + kc + 8);
        uint4 a2 = *(const uint4*)(Ag + kc + 16);
        uint4 a3 = *(const uint4*)(Ag + kc + 24);
        uint4 b0 = *(const uint4*)(Bg + kc);
        uint4 b1 = *(const uint4*)(Bg + kc + 8);
        uint4 b2 = *(const uint4*)(Bg + kc + 16);
        uint4 b3 = *(const uint4*)(Bg + kc + 24);
        *(uint4*)(AsW)    = a0; *(uint4*)(AsW+8)  = a1;
        *(uint4*)(AsW+16) = a2; *(uint4*)(AsW+24) = a3;
        *(uint4*)(BsW)    = b0; *(uint4*)(BsW+8)  = b1;
        *(uint4*)(BsW+16) = b2; *(uint4*)(BsW+24) = b3;
        __syncthreads();
#pragma unroll
        for (int kk = 0; kk < 2; ++kk) {
            v8bf af[4], bb[4];
#pragma unroll
            for (int i=0;i<4;i++) {
                af[i] = *(const v8bf*)&As[(wm*64 + i*16 + l16)*72 + kk*32 + quad*8];
                bb[i] = *(const v8bf*)&Bs[(wn*64 + i*16 + l16)*72 + kk*32 + quad*8];
            }
#pragma unroll
            for (int i=0;i<4;i++)
#pragma unroll
                for (int j=0;j<4;j++)
                    acc[i][j] = __builtin_amdgcn_mfma_f32_16x16x32_bf16(af[i], bb[j], acc[i][j], 0,0,0);
        }
    }

    const int pad = *padp;
    float* rs = (float*)As;          // LDS reuse for row partial sums
    __syncthreads();
    if (tid < 128) rs[tid] = 0.f;
    __syncthreads();
#pragma unroll
    for (int i=0;i<4;i++) {
        float rloc[4] = {0.f,0.f,0.f,0.f};
#pragma unroll
        for (int j=0;j<4;j++) {
#pragma unroll
            for (int r=0;r<4;r++) {
                const int gr = m0 + wm*64 + i*16 + quad*4 + r;
                const int gc = n0 + wn*64 + j*16 + l16;
                const float ex = (gc == pad) ? 0.f : __expf(acc[i][j][r] + bias0[gc]);
                outF[(size_t)gr*VOCABN + gc] = ex;
                rloc[r] += ex;
            }
        }
#pragma unroll
        for (int r=0;r<4;r++)
            atomicAdd(&rs[wm*64 + i*16 + quad*4 + r], rloc[r]);
    }
    __syncthreads();
    if (tid < 128) atomicAdd(&rsum[m0 + tid], rs[tid]);
}

// ---------------- release-free grid barrier ----------------
// All LSTM loop stores are write-through agent-scope atomics (R10 WRITE_SIZE
// evidence: 771 KB = hpk+hallF all reach memory), so there is NO dirty L2 data
// to publish -> the release half (buffer_wbl2) of both old __threadfence()
// calls is dead weight. __syncthreads() emits s_waitcnt vmcnt(0) before
// s_barrier (compiler-enforced), draining the write-through stores to the
// coherence point before tid0's arrival. Only the ACQUIRE side is needed:
// one buffer_inv after the spin so plain cached h loads miss stale L1/L2.
__device__ __forceinline__ void gridbar(int* bar, int target) {
    __syncthreads();     // vmcnt(0): all sc1 stores at coherence point
    if (threadIdx.x == 0) {
        __hip_atomic_fetch_add(bar, 1, __ATOMIC_RELAXED, __HIP_MEMORY_SCOPE_AGENT);
        while (__hip_atomic_load(bar, __ATOMIC_RELAXED, __HIP_MEMORY_SCOPE_AGENT) < target) { }
        __builtin_amdgcn_fence(__ATOMIC_ACQUIRE, "agent");   // buffer_inv only
    }
    __syncthreads();
}

// ---------------- sequential LSTM chain: 4 cooperating CUs, reg-resident W_hh --
// R9 structure (measured 141-152us band): R5 partitioning with loop stores
// moved off the L2 (packed h + hallF via relaxed agent-scope atomic stores;
// hallB eliminated). This round: release-free gridbar (see above) — per step
// the cache-maintenance drops from 2x(wbl2+inv) to 1x inv.
__global__ __launch_bounds__(512, 2) void k_lstm(
    const bf16_t* __restrict__ Whh, const float* __restrict__ xgT,
    const float* __restrict__ c0,
    u32* __restrict__ hpk,           // [16][256] packed (hi | lo<<16)
    float* __restrict__ hallF,
    int* __restrict__ bar)
{
    __shared__ float gl[16][260];   // pre-activation exchange, padded

    const int tid = threadIdx.x;
    const int k = blockIdx.x;            // d-slice owner
    const int w = tid >> 6, lane = tid & 63;
    const int l16 = lane & 15, quad = lane >> 4;

    // B-fragments: wave w owns CU-local cols c in [w*32, w*32+32), ct in {0,1}
    v8bf wb[2][8];
#pragma unroll
    for (int ct = 0; ct < 2; ++ct) {
        const int c = w*32 + ct*16 + l16;
        const int row = (c >> 6)*256 + k*64 + (c & 63);
#pragma unroll
        for (int kc = 0; kc < 8; ++kc)
            wb[ct][kc] = *(const v8bf*)&Whh[(size_t)row*DIM + kc*32 + quad*8];
    }

    float cst[2];
#pragma unroll
    for (int e = 0; e < 2; ++e) {
        const int li = tid + e*512;
        cst[e] = c0[(li >> 6)*DIM + k*64 + (li & 63)];
    }

    for (int step = 0; step < TGT; ++step) {
        // packed h loads (plain cached; gridbar's inv guarantees freshness)
        uint4 pq[8][2];
#pragma unroll
        for (int kc = 0; kc < 8; ++kc) {
            const uint4* pp = (const uint4*)&hpk[l16*DIM + kc*32 + quad*8];
            pq[kc][0] = pp[0]; pq[kc][1] = pp[1];
        }
        // xv: 4 gates of xg for the two owned elements (float4, coalesced)
        float4 xv[2];
#pragma unroll
        for (int e = 0; e < 2; ++e) {
            const int li = tid + e*512;
            const int b = li >> 6, dd = li & 63;
            xv[e] = *(const float4*)&xgT[((size_t)(step*BS + b)*DIM + k*64 + dd)*4];
        }
        // unpack hi/lo
        v8bf ahi[8], alo[8];
#pragma unroll
        for (int kc = 0; kc < 8; ++kc) {
            const u32 uu[8] = {pq[kc][0].x, pq[kc][0].y, pq[kc][0].z, pq[kc][0].w,
                               pq[kc][1].x, pq[kc][1].y, pq[kc][1].z, pq[kc][1].w};
#pragma unroll
            for (int j = 0; j < 8; ++j) {
                union { u32 u; u16 s[2]; } x; x.u = uu[j];
                ahi[kc][j] = *(const bf16_t*)&x.s[0];
                alo[kc][j] = *(const bf16_t*)&x.s[1];
            }
        }

        v4f acc[2] = {(v4f){0.f,0.f,0.f,0.f}, (v4f){0.f,0.f,0.f,0.f}};
#pragma unroll
        for (int kc = 0; kc < 8; ++kc)
#pragma unroll
            for (int ct = 0; ct < 2; ++ct) {
                acc[ct] = __builtin_amdgcn_mfma_f32_16x16x32_bf16(ahi[kc], wb[ct][kc], acc[ct], 0,0,0);
                acc[ct] = __builtin_amdgcn_mfma_f32_16x16x32_bf16(alo[kc], wb[ct][kc], acc[ct], 0,0,0);
            }
        // exchange pre-activations: C row = quad*4+r (b), col = l16 (c-in-tile)
#pragma unroll
        for (int ct = 0; ct < 2; ++ct) {
            const int c = w*32 + ct*16 + l16;
#pragma unroll
            for (int r = 0; r < 4; ++r)
                gl[quad*4 + r][c] = acc[ct][r];
        }
        __syncthreads();
        // elementwise: thread owns (b, dd) and (b+8, dd)
        float hnv[2];
#pragma unroll
        for (int e = 0; e < 2; ++e) {
            const int li = tid + e*512;
            const int b = li >> 6, dd = li & 63;
            const int d = k*64 + dd;
            const float gi = gl[b][dd]        + xv[e].x;
            const float gf = gl[b][64 + dd]   + xv[e].y;
            const float gg = gl[b][128 + dd]  + xv[e].z;
            const float go = gl[b][192 + dd]  + xv[e].w;
            const float si = 1.f/(1.f+__expf(-gi));
            const float sf = 1.f/(1.f+__expf(-gf));
            const float so = 1.f/(1.f+__expf(-go));
            const float cn = sf*cst[e] + si*fast_tanh(gg);
            const float hn = so*fast_tanh(cn);
            cst[e] = cn;
            hnv[e] = hn;
            const bf16_t hi = (bf16_t)hn;
            const bf16_t lo = (bf16_t)(hn - (float)hi);
            const u32 pk = (u32)(*(const u16*)&hi) | ((u32)(*(const u16*)&lo) << 16);
            __hip_atomic_store(&hpk[b*DIM + d], pk, __ATOMIC_RELAXED, __HIP_MEMORY_SCOPE_AGENT);
        }
        if (step < TGT-1) gridbar(bar, (step+1)*LSTM_NBLK);
        // deferred hallF stores: coherence-point writes, off the drain path
#pragma unroll
        for (int e = 0; e < 2; ++e) {
            const int li = tid + e*512;
            const int b = li >> 6, dd = li & 63;
            const int d = k*64 + dd;
            union { float f; u32 u; } cv; cv.f = hnv[e];
            __hip_atomic_store((u32*)&hallF[(size_t)(step*BS + b)*DIM + d], cv.u,
                               __ATOMIC_RELAXED, __HIP_MEMORY_SCOPE_AGENT);
        }
    }
}

// ---------------- expE[t,b,s] = exp(ke[s,b,:] . h[t,b,:]) (device body) --------
__device__ __forceinline__ void escore_body(const int blk, const int tid, float* hS,
    const bf16_t* __restrict__ ke, const float* __restrict__ hallF, float* __restrict__ expE)
{
    const int t = blk >> 4, b = blk & 15;
    hS[tid] = hallF[(size_t)(t*BS + b)*DIM + tid];
    __syncthreads();
    for (int s = tid; s < SRC; s += 256) {
        const v8bf* kp = (const v8bf*)(ke + ((size_t)s*BS + b)*DIM);
        float e = 0.f;
#pragma unroll 8
        for (int m=0;m<32;m++) {
            v8bf kv = kp[m];
#pragma unroll
            for (int i=0;i<8;i++) e += (float)kv[i]*hS[m*8+i];
        }
        expE[((size_t)t*BS + b)*SRC + s] = __expf(e);
    }
}

// fused escore + qd GEMM (qd = h_all @ W_attn_dec, 6 tiles, A32 from hallF)
__global__ __launch_bounds__(256) void k_esq(
    const bf16_t* __restrict__ ke, const float* __restrict__ hallF, float* __restrict__ expE,
    const bf16_t* __restrict__ wadT, bf16_t* __restrict__ qdG)
{
    __shared__ __align__(16) char shb[20480];
    if (blockIdx.x < NROW) {
        escore_body(blockIdx.x, threadIdx.x, (float*)shb, ke, hallF, expE);
        return;
    }
    gemm_tile(threadIdx.x, (bf16_t*)shb, (bf16_t*)(shb + 10240), nullptr, hallF, wadT,
              blockIdx.x - NROW, 256, 256, 2, 2, nullptr, qdG, nullptr, nullptr);
}

// ---------------- in-place inclusive cumulative sum of expE over t ------------
__global__ __launch_bounds__(256) void k_prefix(float* __restrict__ expE)
{
    const int i = blockIdx.x*256 + threadIdx.x;   // flat (b,s)
    if (i >= BS*SRC) return;
    const int b = i / SRC, s = i % SRC;
    float c = 0.f;
    for (int t = 0; t < TGT; ++t) {
        const size_t idx = ((size_t)t*BS + b)*SRC + s;
        c += expE[idx];
        expE[idx] = c;
    }
}

// ---------------- per-(t,b) attention tail (device body) ----------------
// cumE is the CUMULATIVE expE: my = cum[t]-cum[t-1], prev-sum = cum[t-1].
// ce reads he_bf [s][b][d] DIRECTLY (coalesced across threads: consecutive
// tid = consecutive d) — the stride-16KB heT transpose is eliminated.
__device__ void attn_body(char* sh, const int blk, const int tid,
    const float* __restrict__ cumE, const bf16_t* __restrict__ heA,
    const float* __restrict__ hallF, const bf16_t* __restrict__ qdG,
    const float* __restrict__ wu, const float* __restrict__ bu,
    bf16_t* __restrict__ feat, float* __restrict__ Ae, float* __restrict__ ps)
{
    float* hS   = (float*)sh;        // 256
    float* qdS  = hS + 256;          // 256
    float* eeS  = qdS + 256;         // 400
    float* adS  = eeS + 400;         // 24
    float* red  = adS + 24;          // 4
    float* misc = red + 4;           // 2
    const int t = blk >> 4, b = blk & 15;

    hS[tid]  = hallF[(size_t)(t*BS + b)*DIM + tid];
    qdS[tid] = (float)qdG[(size_t)(t*BS + b)*DIM + tid];
    __syncthreads();

    for (int s = tid; s < SRC; s += 256) {
        if (t == 0) {
            eeS[s] = cumE[(size_t)b*SRC + s];               // cum[0] == raw expE
        } else {
            const float prev = cumE[((size_t)(t-1)*BS + b)*SRC + s];
            const float cur  = cumE[((size_t)t*BS + b)*SRC + s];
            eeS[s] = (cur - prev) / prev;
        }
    }
    __syncthreads();
    {   // esum
        float pa = 0.f;
        for (int s = tid; s < SRC; s += 256) pa += eeS[s];
#pragma unroll
        for (int o=32;o>0;o>>=1) pa += __shfl_down(pa, o);
        if ((tid & 63) == 0) red[tid>>6] = pa;
        __syncthreads();
        if (tid == 0) misc[0] = 1.f/(red[0]+red[1]+red[2]+red[3]);
        __syncthreads();
    }
    const float inv_es = misc[0];
    for (int s = tid; s < SRC; s += 256)
        Ae[((size_t)t*BS + b)*SRC + s] = eeS[s] * inv_es;

    float ce;
    {
        const bf16_t* hp = heA + (size_t)b*DIM + tid;   // he[s][b][d], s-stride BS*DIM
        float a0=0.f, a1=0.f, a2=0.f, a3=0.f;
        for (int s = 0; s < SRC; s += 4) {
            a0 += (float)hp[(size_t)(s+0)*BS*DIM] * eeS[s+0];
            a1 += (float)hp[(size_t)(s+1)*BS*DIM] * eeS[s+1];
            a2 += (float)hp[(size_t)(s+2)*BS*DIM] * eeS[s+2];
            a3 += (float)hp[(size_t)(s+3)*BS*DIM] * eeS[s+3];
        }
        ce = ((a0+a1)+(a2+a3)) * inv_es;
    }

    {
        const int wv = tid >> 6, ln = tid & 63;
        for (int tau = wv; tau <= t; tau += 4) {
            float4 a = *(const float4*)(hallF + ((size_t)(tau*BS + b))*DIM + ln*4);
            float e = a.x*qdS[ln*4] + a.y*qdS[ln*4+1] + a.z*qdS[ln*4+2] + a.w*qdS[ln*4+3];
#pragma unroll
            for (int o=32;o>0;o>>=1) e += __shfl_down(e, o);
            if (ln == 0) adS[tau] = __expf(e);
        }
    }
    __syncthreads();
    if (tid < 64) {
        float v = (tid <= t) ? adS[tid] : 0.f;
#pragma unroll
        for (int o=32;o>0;o>>=1) v += __shfl_down(v, o);
        if (tid == 0) misc[1] = 1.f/v;
    }
    __syncthreads();
    float cd = 0.f;
    for (int tau = 0; tau <= t; ++tau)
        cd += adS[tau] * hallF[((size_t)(tau*BS + b))*DIM + tid];
    cd *= misc[1];
    if (t == 0) cd = 0.f;

    const float hd = hS[tid];
    const size_t fr = ((size_t)t*BS + b)*768;
    feat[fr + tid]       = (bf16_t)hd;
    feat[fr + 256 + tid] = (bf16_t)ce;
    feat[fr + 512 + tid] = (bf16_t)cd;
    float pw = hd*wu[tid] + ce*wu[256 + tid] + cd*wu[512 + tid];
#pragma unroll
    for (int o=32;o>0;o>>=1) pw += __shfl_down(pw, o);
    if ((tid & 63) == 0) red[tid>>6] = pw;
    __syncthreads();
    if (tid == 0) {
        float s = red[0]+red[1]+red[2]+red[3];
        ps[t*BS + b] = 1.f/(1.f+__expf(-(s + bu[0])));
    }
}

// ---------------- fused: attention tail (blocks 0-383) + W_out tiles (384-1883) -
__global__ __launch_bounds__(256) void k_attnw(
    const float* __restrict__ cumE, const bf16_t* __restrict__ heA,
    const float* __restrict__ hallF, const bf16_t* __restrict__ qdG,
    const float* __restrict__ wu, const float* __restrict__ bu,
    bf16_t* __restrict__ feat, float* __restrict__ Ae, float* __restrict__ ps,
    const float* __restrict__ Wemb, const bf16_t* __restrict__ wprojT,
    bf16_t* __restrict__ woutB)
{
    __shared__ __align__(16) char shb[20480];
    if (blockIdx.x < NROW) {
        attn_body(shb, blockIdx.x, threadIdx.x, cumE, heA, hallF, qdG, wu, bu, feat, Ae, ps);
        return;
    }
    gemm_tile(threadIdx.x, (bf16_t*)shb, (bf16_t*)(shb + 10240), nullptr, Wemb, wprojT,
              blockIdx.x - NROW, 768, 256, 6, 1,
              nullptr, woutB, nullptr, nullptr);
}

// ---------------- final: scale row by ps[r]/rsum[r], then copy-scatter ---------
__global__ __launch_bounds__(256) void k_final(
    float* __restrict__ out, const float* __restrict__ rsum,
    const float* __restrict__ ps, const int* __restrict__ src,
    const float* __restrict__ Ae)
{
    const int r = blockIdx.x;        // r = t*BS + b
    const int b = r & (BS-1);
    const float p  = ps[r];
    const float sc = p / rsum[r];
    float4* o4 = (float4*)(out + (size_t)r*VOCABN);
    for (int i = threadIdx.x; i < VOCABN/4; i += 256) {
        float4 v = o4[i];
        v.x*=sc; v.y*=sc; v.z*=sc; v.w*=sc;
        o4[i] = v;
    }
    __syncthreads();   // row fully scaled before scatter into it
    for (int s = threadIdx.x; s < SRC; s += 256) {
        const int v = src[s*BS + b];
        atomicAdd(&out[(size_t)r*VOCABN + v], Ae[(size_t)r*SRC + s] * p);
    }
}

// ---------------- workspace layout (bytes, 16B-aligned) ----------------
#define O_WHH    0u
#define O_WADT   524288u
#define O_HEBF   655360u
#define O_KE     7208960u
#define O_WAE    10485760u
#define O_WPROJT 10616832u
#define O_WIH    11010048u
#define O_EMBA   11534336u
#define O_WOUT   11730944u
#define O_XG     60882944u
#define O_HALLF  62455808u
#define O_QD     63045632u
#define O_EXPE   63242240u   // first 16 KB double as hpk (packed h) during k_lstm
#define O_FEAT   63856640u
#define O_AE     64446464u
#define O_PS     65060864u
#define O_BAR    65062400u   // barrier counter + rsum, zeroed by k_prep each call
#define O_RSUM   65063936u

extern "C" void kernel_launch(void* const* d_in, const int* in_sizes, int n_in,
                              void* d_out, int out_size, void* d_ws, size_t ws_size,
                              hipStream_t stream)
{
    const int*   inputs = (const int*)  d_in[0];
    const int*   src    = (const int*)  d_in[1];
    const float* h_e    = (const float*)d_in[2];
    const float* h0     = (const float*)d_in[3];
    const float* c0     = (const float*)d_in[4];
    const float* W_emb  = (const float*)d_in[5];
    const float* W_ih   = (const float*)d_in[6];
    const float* b_ih   = (const float*)d_in[7];
    const float* W_hh   = (const float*)d_in[8];
    const float* b_hh   = (const float*)d_in[9];
    const float* W_ae   = (const float*)d_in[10];
    const float* W_ad   = (const float*)d_in[11];
    const float* W_proj = (const float*)d_in[12];
    const float* W_u    = (const float*)d_in[13];
    const float* b_u    = (const float*)d_in[14];
    const float* b_out  = (const float*)d_in[15];
    const int*   pad_id = (const int*)  d_in[16];

    char* w = (char*)d_ws;
    bf16_t* whh_bf  = (bf16_t*)(w + O_WHH);
    bf16_t* wadT_bf = (bf16_t*)(w + O_WADT);
    bf16_t* he_bf   = (bf16_t*)(w + O_HEBF);
    bf16_t* ke_bf   = (bf16_t*)(w + O_KE);
    bf16_t* wae_bf  = (bf16_t*)(w + O_WAE);
    bf16_t* wprojT  = (bf16_t*)(w + O_WPROJT);
    bf16_t* wih_bf  = (bf16_t*)(w + O_WIH);
    bf16_t* embA_bf = (bf16_t*)(w + O_EMBA);
    bf16_t* wout_bf = (bf16_t*)(w + O_WOUT);
    float*  xg      = (float*) (w + O_XG);      // holds xgT: [row][d][gate]
    float*  hallF   = (float*) (w + O_HALLF);
    bf16_t* qdG     = (bf16_t*)(w + O_QD);
    float*  expE    = (float*) (w + O_EXPE);
    u32*    hpk     = (u32*)   (w + O_EXPE);          // 16 KB, dead until k_esq
    bf16_t* feat_bf = (bf16_t*)(w + O_FEAT);
    float*  Ae      = (float*) (w + O_AE);
    float*  ps      = (float*) (w + O_PS);
    int*    bar     = (int*)   (w + O_BAR);
    u32*    zeroreg = (u32*)   (w + O_BAR);           // bar + rsum, 3072 B
    float*  rsum    = (float*) (w + O_RSUM);
    float*  out     = (float*)d_out;

    // prep: coalesced conversions only (+ zeroes bar/rsum, packs h0)
    k_prep<<<1024, 256, 0, stream>>>(W_hh, h_e, W_emb, W_ae, W_ih, inputs, h0,
                                     whh_bf, he_bf, wae_bf, wih_bf,
                                     embA_bf, hpk, zeroreg);
    // xgT (24 tiles) + ke (100 tiles) + wproj/wad LDS-tiled transposes (64)
    k_gemm2<<<188, 256, 0, stream>>>(embA_bf, wih_bf, xg, b_ih, b_hh,
                                     he_bf, wae_bf, ke_bf,
                                     W_proj, wprojT, W_ad, wadT_bf);
    // cooperative 4-CU LSTM chain, register-resident W_hh, release-free gridbar
    k_lstm<<<LSTM_NBLK, 512, 0, stream>>>(whh_bf, xg, c0, hpk, hallF, bar);
    // fused escore (blocks 0-383) + qd GEMM (blocks 384-389, A32 from hallF)
    k_esq<<<NROW + 6, 256, 0, stream>>>(ke_bf, hallF, expE, wadT_bf, qdG);
    // in-place cumulative sum of expE over t (25 blocks)
    k_prefix<<<25, 256, 0, stream>>>(expE);
    // fused attention tail (0-383) + W_out GEMM (384-1883)
    k_attnw<<<NROW + 1500, 256, 0, stream>>>(expE, he_bf, hallF, qdG, W_u, b_u,
                                             feat_bf, Ae, ps,
                                             W_emb, wprojT, wout_bf);
    // exp(logits + b_out), pad -> 0, + fused row sums  (M=384, N=32000, K=768)
    k_gemm3<<<750, 256, 0, stream>>>(feat_bf, wout_bf, out, b_out, pad_id, rsum);
    // scale + copy-scatter, one block per row
    k_final<<<NROW, 256, 0, stream>>>(out, rsum, ps, src, Ae);
}